// Round 5
// baseline (343.971 us; speedup 1.0000x reference)
//
#include <hip/hip_runtime.h>
#include <hip/hip_bf16.h>
#include <math.h>

#define B_   2
#define N_   6
#define CC   256
#define OCH  64
#define DBN  59
#define FH_  16
#define FW_  44
#define PXI  (FH_*FW_)             // 704
#define NPIX (B_*N_*PXI)           // 8448
#define NPTS (B_*N_*DBN*PXI)       // 498432
#define NX_  128
#define NY_  128
#define NCELL (B_*NY_*NX_)         // 32768
#define NOUT 123
#define OUTSZ (B_*OCH*NY_*NX_)     // 2097152
#define TCH  128                   // gather chunk (slots per wave)

#define XSTEP (703.0f/43.0f)
#define YSTEP (255.0f/15.0f)

// ---------------------------------------------------------------------------
// comb = rots @ inv(intrins): f32, non-contracted, bit-identical to the
// validated round-1..4 ordering.
// ---------------------------------------------------------------------------
__device__ __forceinline__ void comb_cam(const float* __restrict__ R,
                                         const float* __restrict__ K,
                                         float* __restrict__ out9) {
    float a = K[0], b = K[1], c = K[2];
    float d = K[3], e = K[4], f = K[5];
    float g = K[6], h = K[7], k = K[8];
    float A  =  __fsub_rn(__fmul_rn(e, k), __fmul_rn(f, h));
    float Bc = -__fsub_rn(__fmul_rn(d, k), __fmul_rn(f, g));
    float Cc =  __fsub_rn(__fmul_rn(d, h), __fmul_rn(e, g));
    float det = __fadd_rn(__fadd_rn(__fmul_rn(a, A), __fmul_rn(b, Bc)),
                          __fmul_rn(c, Cc));
    float inv[9];
    inv[0] = __fdiv_rn(A, det);
    inv[1] = __fdiv_rn(-__fsub_rn(__fmul_rn(b, k), __fmul_rn(c, h)), det);
    inv[2] = __fdiv_rn( __fsub_rn(__fmul_rn(b, f), __fmul_rn(c, e)), det);
    inv[3] = __fdiv_rn(Bc, det);
    inv[4] = __fdiv_rn( __fsub_rn(__fmul_rn(a, k), __fmul_rn(c, g)), det);
    inv[5] = __fdiv_rn(-__fsub_rn(__fmul_rn(a, f), __fmul_rn(c, d)), det);
    inv[6] = __fdiv_rn(Cc, det);
    inv[7] = __fdiv_rn(-__fsub_rn(__fmul_rn(a, h), __fmul_rn(b, g)), det);
    inv[8] = __fdiv_rn( __fsub_rn(__fmul_rn(a, e), __fmul_rn(b, d)), det);
    for (int r = 0; r < 3; ++r)
        for (int cc = 0; cc < 3; ++cc) {
            float s =        __fmul_rn(R[r*3+0], inv[0*3+cc]);
            s = __fadd_rn(s, __fmul_rn(R[r*3+1], inv[1*3+cc]));
            s = __fadd_rn(s, __fmul_rn(R[r*3+2], inv[2*3+cc]));
            out9[r*3 + cc] = s;
        }
}

// ---------------------------------------------------------------------------
// Kernel 1: 1x1 conv (256 -> 123), 8 outputs per wave, + zero-fill.
// 16 o-groups x 132 pixel-groups = 2112 waves = 528 blocks.
// ---------------------------------------------------------------------------
__global__ __launch_bounds__(256) void k_conv(
        const float* __restrict__ x, const float* __restrict__ wgt,
        const float* __restrict__ bias,
        float* __restrict__ dlog, float* __restrict__ ctx_ws,
        float* __restrict__ out, unsigned* __restrict__ cellofs) {
    const int gid = blockIdx.x * 256 + threadIdx.x;
    const int stride = 528 * 256;
    float4* o4 = (float4*)out;
    for (int i = gid; i < OUTSZ / 4; i += stride)
        o4[i] = make_float4(0.f, 0.f, 0.f, 0.f);
    for (int i = gid; i < NCELL; i += stride) cellofs[i] = 0u;

    const int wv = gid >> 6;
    const int lane = threadIdx.x & 63;
    int og = wv / 132;
    const int pg = wv - og * 132;
    og = __builtin_amdgcn_readfirstlane(og);
    const int o0 = og * 8;
    const int pix = pg * 64 + lane;
    const int bn = pix / PXI;
    const int q  = pix - bn * PXI;
    const float* xp = x + (size_t)bn * CC * PXI + q;

    const float* wp[8];
    float bv[8];
    #pragma unroll
    for (int kk = 0; kk < 8; ++kk) {
        int o = o0 + kk; if (o > NOUT - 1) o = NOUT - 1;
        wp[kk] = wgt + (size_t)o * CC;
        bv[kk] = bias[o];
    }
    float acc[8] = {0.f, 0.f, 0.f, 0.f, 0.f, 0.f, 0.f, 0.f};
    #pragma unroll 4
    for (int c = 0; c < CC; ++c) {
        const float xv = xp[(size_t)c * PXI];
        #pragma unroll
        for (int kk = 0; kk < 8; ++kk)
            acc[kk] = fmaf(xv, wp[kk][c], acc[kk]);
    }
    #pragma unroll
    for (int kk = 0; kk < 8; ++kk) {
        const int o = o0 + kk;
        if (o >= NOUT) break;
        const float a = acc[kk] + bv[kk];
        if (o < DBN) dlog[(size_t)o * NPIX + pix] = a;
        else         ctx_ws[(size_t)pix * OCH + (o - DBN)] = a;
    }
}

// ---------------------------------------------------------------------------
// Kernel 2: per-POINT geometry + wave-aggregated histogram; per-pixel
// softmax stats (m, 1/s) folded in for threads with pt < NPIX.
// ---------------------------------------------------------------------------
__global__ __launch_bounds__(256) void k_geom(
        const float* __restrict__ rots, const float* __restrict__ intrins,
        const float* __restrict__ trans, const float* __restrict__ dlog,
        float2* __restrict__ msum, unsigned short* __restrict__ cell16,
        unsigned* __restrict__ cellofs) {
    __shared__ float combs[B_ * N_ * 9];
    __shared__ float trs[B_ * N_ * 3];
    const int t = threadIdx.x;
    if (t < B_ * N_) comb_cam(rots + t * 9, intrins + t * 9, &combs[t * 9]);
    if (t < B_ * N_ * 3) trs[t] = trans[t];
    __syncthreads();

    const int pt = blockIdx.x * 256 + t;           // grid exact: 1947*256
    const int q  = pt % PXI;
    const int r  = pt / PXI;
    const int dq = r % DBN;
    const int bn = r / DBN;
    const int hq = q / FW_;
    const int wq = q - hq * FW_;
    const int bq = bn / N_;

    const float* cb = &combs[bn * 9];
    const float t0 = trs[bn*3+0], t1 = trs[bn*3+1], t2 = trs[bn*3+2];

    const float dsv = __fadd_rn(1.0f, (float)dq);
    const float xsv = __fmul_rn((float)wq, XSTEP);
    const float ysv = __fmul_rn((float)hq, YSTEP);
    const float px = __fmul_rn(xsv, dsv);
    const float py = __fmul_rn(ysv, dsv);
    const float pz = dsv;
    float gx = __fadd_rn(__fadd_rn(__fmul_rn(cb[0], px), __fmul_rn(cb[1], py)),
                         __fmul_rn(cb[2], pz));
    float gy = __fadd_rn(__fadd_rn(__fmul_rn(cb[3], px), __fmul_rn(cb[4], py)),
                         __fmul_rn(cb[5], pz));
    float gz = __fadd_rn(__fadd_rn(__fmul_rn(cb[6], px), __fmul_rn(cb[7], py)),
                         __fmul_rn(cb[8], pz));
    gx = __fadd_rn(gx, t0);
    gy = __fadd_rn(gy, t1);
    gz = __fadd_rn(gz, t2);

    const float bxv = -50.8f;
    const float lbx = __fsub_rn(bxv, 0.4f);
    const float lbz = -10.0f;
    const int cx = (int)floorf(__fdiv_rn(__fsub_rn(gx, lbx), 0.8f));
    const int cy = (int)floorf(__fdiv_rn(__fsub_rn(gy, lbx), 0.8f));
    const int cz = (int)floorf(__fdiv_rn(__fsub_rn(gz, lbz), 20.0f));

    int c = -1;
    if (cx >= 0 && cx < NX_ && cy >= 0 && cy < NY_ && cz == 0)
        c = bq * (NY_ * NX_) + cy * NX_ + cx;
    cell16[pt] = (c >= 0) ? (unsigned short)c : (unsigned short)0xFFFFu;

    // wave-aggregated histogram: one atomic per distinct cell per wave
    const int lane = t & 63;
    unsigned long long active = __ballot(c >= 0);
    while (active) {
        const int leader = (int)__ffsll((unsigned long long)active) - 1;
        const int lc = __shfl(c, leader);
        const unsigned long long same = __ballot(c == lc);
        if (lane == leader)
            atomicAdd(&cellofs[lc], (unsigned)__popcll(same));
        active &= ~same;
    }

    // per-pixel softmax stats (two-pass, low VGPR)
    if (pt < NPIX) {
        float m = -1e30f;
        for (int d = 0; d < DBN; ++d)
            m = fmaxf(m, dlog[(size_t)d * NPIX + pt]);
        float s = 0.f;
        for (int d = 0; d < DBN; ++d)
            s += expf(dlog[(size_t)d * NPIX + pt] - m);
        msum[pt] = make_float2(m, 1.0f / s);
    }
}

// ---------------------------------------------------------------------------
// Kernel 3: in-place exclusive scan of cellofs[32768]. One block, 1024 thr.
// ---------------------------------------------------------------------------
__global__ __launch_bounds__(1024) void k_scan(unsigned* __restrict__ cellofs) {
    __shared__ unsigned lds[2][1024];
    const int t = threadIdx.x;
    uint4 u[8];
    const uint4* src4 = (const uint4*)cellofs + (size_t)t * 8;
    #pragma unroll
    for (int i = 0; i < 8; ++i) u[i] = src4[i];
    unsigned vv[32];
    unsigned run = 0;
    #pragma unroll
    for (int i = 0; i < 8; ++i) {
        vv[i*4+0] = run; run += u[i].x;
        vv[i*4+1] = run; run += u[i].y;
        vv[i*4+2] = run; run += u[i].z;
        vv[i*4+3] = run; run += u[i].w;
    }
    lds[0][t] = run;
    __syncthreads();
    int src = 0;
    for (int off = 1; off < 1024; off <<= 1) {
        unsigned val = lds[src][t];
        if (t >= off) val += lds[src][t - off];
        lds[1 - src][t] = val;
        __syncthreads();
        src = 1 - src;
    }
    const unsigned base = (t == 0) ? 0u : lds[src][t - 1];
    uint4* dst4 = (uint4*)cellofs + (size_t)t * 8;
    #pragma unroll
    for (int i = 0; i < 8; ++i) {
        uint4 w;
        w.x = base + vv[i*4+0];
        w.y = base + vv[i*4+1];
        w.z = base + vv[i*4+2];
        w.w = base + vv[i*4+3];
        dst4[i] = w;
    }
}

// ---------------------------------------------------------------------------
// Kernel 4: fill CSR slots. Wave-aggregated cursor atomics; weight computed
// here as exp(dlog - m) * invs. srt[slot] = {(cell<<14)|pix, bits(w)}.
// ---------------------------------------------------------------------------
__global__ __launch_bounds__(256) void k_fill(
        const unsigned short* __restrict__ cell16,
        const float* __restrict__ dlog, const float2* __restrict__ msum,
        unsigned* __restrict__ cellofs, uint2* __restrict__ srt) {
    const int pt = blockIdx.x * 256 + threadIdx.x;
    const unsigned cc = cell16[pt];
    const int c = (cc == 0xFFFFu) ? -1 : (int)cc;
    const int lane = threadIdx.x & 63;

    unsigned slot = 0;
    unsigned long long active = __ballot(c >= 0);
    while (active) {
        const int leader = (int)__ffsll((unsigned long long)active) - 1;
        const int lc = __shfl(c, leader);
        const unsigned long long same = __ballot(c == lc);
        unsigned b0 = 0;
        if (lane == leader)
            b0 = atomicAdd(&cellofs[lc], (unsigned)__popcll(same));
        b0 = __shfl(b0, leader);
        if (c == lc)
            slot = b0 + (unsigned)__popcll(same & ((1ULL << lane) - 1ULL));
        active &= ~same;
    }

    if (c >= 0) {
        const int q  = pt % PXI;
        const int r  = pt / PXI;
        const int dq = r % DBN;
        const int bn = r / DBN;
        const int pix = bn * PXI + q;
        const float2 ms = msum[pix];
        const float w = expf(dlog[(size_t)dq * NPIX + pix] - ms.x) * ms.y;
        srt[slot] = make_uint2(((unsigned)c << 14) | (unsigned)pix,
                               __float_as_uint(w));
    }
}

// ---------------------------------------------------------------------------
// Kernel 5: atomic-free gather with run ownership. A chunk owns every run
// STARTING inside [base, base+TCH); it skips a continuation head and extends
// its last run past the chunk end. All stores plain (out pre-zeroed).
// Control flow is wave-uniform (srt loads broadcast); lane = channel.
// ---------------------------------------------------------------------------
__device__ __forceinline__ void cell_store(float* __restrict__ out,
                                           unsigned cell, int ch, float acc) {
    const int b  = (int)(cell >> 14);
    const int cy = (int)((cell >> 7) & 127u);
    const int cx = (int)(cell & 127u);
    out[(((size_t)(b * OCH + ch)) * NY_ + cy) * NX_ + cx] = acc;
}

__global__ __launch_bounds__(256) void k_gather(
        const unsigned* __restrict__ cellofs, const uint2* __restrict__ srt,
        const float* __restrict__ ctx_ws, float* __restrict__ out) {
    const int wid = (blockIdx.x * 256 + threadIdx.x) >> 6;
    const int ch = threadIdx.x & 63;
    const unsigned K = cellofs[NCELL - 1];
    const unsigned base = (unsigned)wid * TCH;
    if (base >= K) return;
    const unsigned ownEnd = base + TCH;
    unsigned i = base;

    if (base > 0) {
        const unsigned pc = srt[base - 1].x >> 14;
        for (;;) {
            const unsigned lim = (ownEnd < K) ? ownEnd : K;
            unsigned n = lim - i; if (n > 8u) n = 8u;
            if (n == 0u) return;                 // chunk is all continuation
            unsigned c8[8];
            #pragma unroll
            for (unsigned j = 0; j < 8u; ++j)
                if (j < n) c8[j] = srt[i + j].x >> 14;
            unsigned adv = 0; bool stop = false;
            #pragma unroll
            for (unsigned j = 0; j < 8u; ++j) {
                if (j < n && !stop) {
                    if (c8[j] == pc) ++adv; else stop = true;
                }
            }
            i += adv;
            if (stop) break;
        }
    }

    unsigned cur = srt[i].x >> 14;
    float acc = 0.f;
    for (;;) {
        unsigned n = K - i; if (n > 8u) n = 8u;
        uint2 r8[8]; float v8[8];
        #pragma unroll
        for (unsigned j = 0; j < 8u; ++j)
            if (j < n) r8[j] = srt[i + j];
        #pragma unroll
        for (unsigned j = 0; j < 8u; ++j)
            if (j < n) v8[j] = ctx_ws[(size_t)(r8[j].x & 0x3FFFu) * OCH + ch];
        bool done = false;
        #pragma unroll
        for (unsigned j = 0; j < 8u; ++j) {
            if (j < n && !done) {
                const unsigned c = r8[j].x >> 14;
                if (c != cur) {
                    cell_store(out, cur, ch, acc);
                    if (i + j >= ownEnd) { done = true; }
                    else { cur = c; acc = 0.f; }
                }
                if (!done) acc = fmaf(__uint_as_float(r8[j].y), v8[j], acc);
            }
        }
        if (done) return;
        i += n;
        if (i >= K) { cell_store(out, cur, ch, acc); return; }
    }
}

// ---------------------------------------------------------------------------
extern "C" void kernel_launch(void* const* d_in, const int* in_sizes, int n_in,
                              void* d_out, int out_size, void* d_ws, size_t ws_size,
                              hipStream_t stream) {
    const float* x       = (const float*)d_in[0];
    const float* rots    = (const float*)d_in[1];
    const float* trans   = (const float*)d_in[2];
    const float* intrins = (const float*)d_in[3];
    const float* depth_w = (const float*)d_in[4];
    const float* depth_b = (const float*)d_in[5];
    float* out = (float*)d_out;

    float* ws = (float*)d_ws;
    size_t off = 0;
    float* dlog     = ws + off; off += (size_t)DBN * NPIX;      // 498432
    float* ctx_ws   = ws + off; off += (size_t)NPIX * OCH;      // 540672
    float2* msum    = (float2*)(ws + off); off += (size_t)NPIX * 2; // 16896
    unsigned* cellofs = (unsigned*)(ws + off); off += NCELL;    // 32768
    unsigned short* cell16 = (unsigned short*)(ws + off);
    off += (size_t)NPTS / 2;                                    // 249216
    uint2* srt      = (uint2*)(ws + off); off += (size_t)NPTS * 2; // 996864
    // total ~9.3 MB of d_ws; all offsets 8B-aligned.

    k_conv<<<528, 256, 0, stream>>>(x, depth_w, depth_b, dlog, ctx_ws,
                                    out, cellofs);
    k_geom<<<NPTS / 256, 256, 0, stream>>>(rots, intrins, trans, dlog,
                                           msum, cell16, cellofs);
    k_scan<<<1, 1024, 0, stream>>>(cellofs);
    k_fill<<<NPTS / 256, 256, 0, stream>>>(cell16, dlog, msum, cellofs, srt);
    const int gwaves = NPTS / TCH;                 // 3894
    k_gather<<<(gwaves + 3) / 4, 256, 0, stream>>>(cellofs, srt, ctx_ws, out);
}

// Round 6
// 247.512 us; speedup vs baseline: 1.3897x; 1.3897x over previous
//
#include <hip/hip_runtime.h>
#include <hip/hip_bf16.h>
#include <math.h>

#define B_   2
#define N_   6
#define CC   256
#define OCH  64
#define DBN  59
#define FH_  16
#define FW_  44
#define PXI  (FH_*FW_)             // 704
#define NPIX (B_*N_*PXI)           // 8448
#define NPTS (B_*N_*DBN*PXI)       // 498432
#define NX_  128
#define NY_  128
#define NCELL (B_*NY_*NX_)         // 32768
#define NOUT 123
#define OUTSZ (B_*OCH*NY_*NX_)     // 2097152
#define TCH  64                    // gather chunk (slots per wave)
#define OG   16                    // conv outputs per wave

#define XSTEP (703.0f/43.0f)
#define YSTEP (255.0f/15.0f)

// ---------------------------------------------------------------------------
// comb = rots @ inv(intrins): f32, non-contracted, bit-identical to the
// validated round-1..5 ordering.
// ---------------------------------------------------------------------------
__device__ __forceinline__ void comb_cam(const float* __restrict__ R,
                                         const float* __restrict__ K,
                                         float* __restrict__ out9) {
    float a = K[0], b = K[1], c = K[2];
    float d = K[3], e = K[4], f = K[5];
    float g = K[6], h = K[7], k = K[8];
    float A  =  __fsub_rn(__fmul_rn(e, k), __fmul_rn(f, h));
    float Bc = -__fsub_rn(__fmul_rn(d, k), __fmul_rn(f, g));
    float Cc =  __fsub_rn(__fmul_rn(d, h), __fmul_rn(e, g));
    float det = __fadd_rn(__fadd_rn(__fmul_rn(a, A), __fmul_rn(b, Bc)),
                          __fmul_rn(c, Cc));
    float inv[9];
    inv[0] = __fdiv_rn(A, det);
    inv[1] = __fdiv_rn(-__fsub_rn(__fmul_rn(b, k), __fmul_rn(c, h)), det);
    inv[2] = __fdiv_rn( __fsub_rn(__fmul_rn(b, f), __fmul_rn(c, e)), det);
    inv[3] = __fdiv_rn(Bc, det);
    inv[4] = __fdiv_rn( __fsub_rn(__fmul_rn(a, k), __fmul_rn(c, g)), det);
    inv[5] = __fdiv_rn(-__fsub_rn(__fmul_rn(a, f), __fmul_rn(c, d)), det);
    inv[6] = __fdiv_rn(Cc, det);
    inv[7] = __fdiv_rn(-__fsub_rn(__fmul_rn(a, h), __fmul_rn(b, g)), det);
    inv[8] = __fdiv_rn( __fsub_rn(__fmul_rn(a, e), __fmul_rn(b, d)), det);
    for (int r = 0; r < 3; ++r)
        for (int cc = 0; cc < 3; ++cc) {
            float s =        __fmul_rn(R[r*3+0], inv[0*3+cc]);
            s = __fadd_rn(s, __fmul_rn(R[r*3+1], inv[1*3+cc]));
            s = __fadd_rn(s, __fmul_rn(R[r*3+2], inv[2*3+cc]));
            out9[r*3 + cc] = s;
        }
}

// ---------------------------------------------------------------------------
// Kernel 1: 1x1 conv (256 -> 123), 16 outputs per wave, + zero-fill.
// 8 o-groups x 132 pixel-groups = 1056 waves = 264 blocks.
// ---------------------------------------------------------------------------
__global__ __launch_bounds__(256) void k_conv(
        const float* __restrict__ x, const float* __restrict__ wgt,
        const float* __restrict__ bias,
        float* __restrict__ dlog, float* __restrict__ ctx_ws,
        float* __restrict__ out, unsigned* __restrict__ cellofs) {
    const int gid = blockIdx.x * 256 + threadIdx.x;
    const int stride = 264 * 256;
    float4* o4 = (float4*)out;
    for (int i = gid; i < OUTSZ / 4; i += stride)
        o4[i] = make_float4(0.f, 0.f, 0.f, 0.f);
    for (int i = gid; i < NCELL; i += stride) cellofs[i] = 0u;

    const int wv = gid >> 6;
    const int lane = threadIdx.x & 63;
    int og = wv / 132;
    const int pg = wv - og * 132;
    og = __builtin_amdgcn_readfirstlane(og);
    const int o0 = og * OG;
    const int pix = pg * 64 + lane;
    const int bn = pix / PXI;
    const int q  = pix - bn * PXI;
    const float* xp = x + (size_t)bn * CC * PXI + q;

    float acc[OG];
    #pragma unroll
    for (int kk = 0; kk < OG; ++kk) acc[kk] = 0.f;

    #pragma unroll 4
    for (int c = 0; c < CC; ++c) {
        const float xv = xp[(size_t)c * PXI];
        #pragma unroll
        for (int kk = 0; kk < OG; ++kk) {
            int o = o0 + kk; if (o > NOUT - 1) o = NOUT - 1;
            acc[kk] = fmaf(xv, wgt[(size_t)o * CC + c], acc[kk]);
        }
    }
    #pragma unroll
    for (int kk = 0; kk < OG; ++kk) {
        const int o = o0 + kk;
        if (o >= NOUT) break;
        const float a = acc[kk] + bias[o];
        if (o < DBN) dlog[(size_t)o * NPIX + pix] = a;
        else         ctx_ws[(size_t)pix * OCH + (o - DBN)] = a;
    }
}

// ---------------------------------------------------------------------------
// Kernel 2: per-POINT geometry + wave-aggregated histogram; per-pixel
// softmax stats (m, 1/s) folded in for threads with pt < NPIX.
// ---------------------------------------------------------------------------
__global__ __launch_bounds__(256) void k_geom(
        const float* __restrict__ rots, const float* __restrict__ intrins,
        const float* __restrict__ trans, const float* __restrict__ dlog,
        float2* __restrict__ msum, unsigned short* __restrict__ cell16,
        unsigned* __restrict__ cellofs) {
    __shared__ float combs[B_ * N_ * 9];
    __shared__ float trs[B_ * N_ * 3];
    const int t = threadIdx.x;
    if (t < B_ * N_) comb_cam(rots + t * 9, intrins + t * 9, &combs[t * 9]);
    if (t < B_ * N_ * 3) trs[t] = trans[t];
    __syncthreads();

    const int pt = blockIdx.x * 256 + t;           // grid exact: 1947*256
    const int q  = pt % PXI;
    const int r  = pt / PXI;
    const int dq = r % DBN;
    const int bn = r / DBN;
    const int hq = q / FW_;
    const int wq = q - hq * FW_;
    const int bq = bn / N_;

    const float* cb = &combs[bn * 9];
    const float t0 = trs[bn*3+0], t1 = trs[bn*3+1], t2 = trs[bn*3+2];

    const float dsv = __fadd_rn(1.0f, (float)dq);
    const float xsv = __fmul_rn((float)wq, XSTEP);
    const float ysv = __fmul_rn((float)hq, YSTEP);
    const float px = __fmul_rn(xsv, dsv);
    const float py = __fmul_rn(ysv, dsv);
    const float pz = dsv;
    float gx = __fadd_rn(__fadd_rn(__fmul_rn(cb[0], px), __fmul_rn(cb[1], py)),
                         __fmul_rn(cb[2], pz));
    float gy = __fadd_rn(__fadd_rn(__fmul_rn(cb[3], px), __fmul_rn(cb[4], py)),
                         __fmul_rn(cb[5], pz));
    float gz = __fadd_rn(__fadd_rn(__fmul_rn(cb[6], px), __fmul_rn(cb[7], py)),
                         __fmul_rn(cb[8], pz));
    gx = __fadd_rn(gx, t0);
    gy = __fadd_rn(gy, t1);
    gz = __fadd_rn(gz, t2);

    const float bxv = -50.8f;
    const float lbx = __fsub_rn(bxv, 0.4f);
    const float lbz = -10.0f;
    const int cx = (int)floorf(__fdiv_rn(__fsub_rn(gx, lbx), 0.8f));
    const int cy = (int)floorf(__fdiv_rn(__fsub_rn(gy, lbx), 0.8f));
    const int cz = (int)floorf(__fdiv_rn(__fsub_rn(gz, lbz), 20.0f));

    int c = -1;
    if (cx >= 0 && cx < NX_ && cy >= 0 && cy < NY_ && cz == 0)
        c = bq * (NY_ * NX_) + cy * NX_ + cx;
    cell16[pt] = (c >= 0) ? (unsigned short)c : (unsigned short)0xFFFFu;

    // wave-aggregated histogram: one atomic per distinct cell per wave
    const int lane = t & 63;
    unsigned long long active = __ballot(c >= 0);
    while (active) {
        const int leader = (int)__ffsll((unsigned long long)active) - 1;
        const int lc = __shfl(c, leader);
        const unsigned long long same = __ballot(c == lc);
        if (lane == leader)
            atomicAdd(&cellofs[lc], (unsigned)__popcll(same));
        active &= ~same;
    }

    // per-pixel softmax stats (two-pass, low VGPR)
    if (pt < NPIX) {
        float m = -1e30f;
        for (int d = 0; d < DBN; ++d)
            m = fmaxf(m, dlog[(size_t)d * NPIX + pt]);
        float s = 0.f;
        for (int d = 0; d < DBN; ++d)
            s += expf(dlog[(size_t)d * NPIX + pt] - m);
        msum[pt] = make_float2(m, 1.0f / s);
    }
}

// ---------------------------------------------------------------------------
// Kernel 3: in-place exclusive scan of cellofs[32768]. One block, 1024 thr.
// ---------------------------------------------------------------------------
__global__ __launch_bounds__(1024) void k_scan(unsigned* __restrict__ cellofs) {
    __shared__ unsigned lds[2][1024];
    const int t = threadIdx.x;
    uint4 u[8];
    const uint4* src4 = (const uint4*)cellofs + (size_t)t * 8;
    #pragma unroll
    for (int i = 0; i < 8; ++i) u[i] = src4[i];
    unsigned vv[32];
    unsigned run = 0;
    #pragma unroll
    for (int i = 0; i < 8; ++i) {
        vv[i*4+0] = run; run += u[i].x;
        vv[i*4+1] = run; run += u[i].y;
        vv[i*4+2] = run; run += u[i].z;
        vv[i*4+3] = run; run += u[i].w;
    }
    lds[0][t] = run;
    __syncthreads();
    int src = 0;
    for (int off = 1; off < 1024; off <<= 1) {
        unsigned val = lds[src][t];
        if (t >= off) val += lds[src][t - off];
        lds[1 - src][t] = val;
        __syncthreads();
        src = 1 - src;
    }
    const unsigned base = (t == 0) ? 0u : lds[src][t - 1];
    uint4* dst4 = (uint4*)cellofs + (size_t)t * 8;
    #pragma unroll
    for (int i = 0; i < 8; ++i) {
        uint4 w;
        w.x = base + vv[i*4+0];
        w.y = base + vv[i*4+1];
        w.z = base + vv[i*4+2];
        w.w = base + vv[i*4+3];
        dst4[i] = w;
    }
}

// ---------------------------------------------------------------------------
// Kernel 4: fill CSR slots. Wave-aggregated cursor atomics; weight computed
// here as exp(dlog - m) * invs. srt[slot] = {(cell<<14)|pix, bits(w)}.
// ---------------------------------------------------------------------------
__global__ __launch_bounds__(256) void k_fill(
        const unsigned short* __restrict__ cell16,
        const float* __restrict__ dlog, const float2* __restrict__ msum,
        unsigned* __restrict__ cellofs, uint2* __restrict__ srt) {
    const int pt = blockIdx.x * 256 + threadIdx.x;
    const unsigned cc = cell16[pt];
    const int c = (cc == 0xFFFFu) ? -1 : (int)cc;
    const int lane = threadIdx.x & 63;

    unsigned slot = 0;
    unsigned long long active = __ballot(c >= 0);
    while (active) {
        const int leader = (int)__ffsll((unsigned long long)active) - 1;
        const int lc = __shfl(c, leader);
        const unsigned long long same = __ballot(c == lc);
        unsigned b0 = 0;
        if (lane == leader)
            b0 = atomicAdd(&cellofs[lc], (unsigned)__popcll(same));
        b0 = __shfl(b0, leader);
        if (c == lc)
            slot = b0 + (unsigned)__popcll(same & ((1ULL << lane) - 1ULL));
        active &= ~same;
    }

    if (c >= 0) {
        const int q  = pt % PXI;
        const int r  = pt / PXI;
        const int dq = r % DBN;
        const int bn = r / DBN;
        const int pix = bn * PXI + q;
        const float2 ms = msum[pix];
        const float w = expf(dlog[(size_t)dq * NPIX + pix] - ms.x) * ms.y;
        srt[slot] = make_uint2(((unsigned)c << 14) | (unsigned)pix,
                               __float_as_uint(w));
    }
}

// ---------------------------------------------------------------------------
// Kernel 5: load-balanced chunked gather (round-4 proven structure, TCH=64).
// wave = chunk, lane = channel. Runs interior to the chunk -> plain store;
// first/last run of the chunk -> atomicAdd (runs split across chunks).
// Meta loads wave-uniform (scalar); ctx reads coalesced 256B, L2-resident.
// ---------------------------------------------------------------------------
__device__ __forceinline__ void flush_cell(float* __restrict__ out, unsigned cell,
                                           int ch, float acc, bool use_atomic) {
    const int b  = (int)(cell >> 14);
    const int cy = (int)((cell >> 7) & 127u);
    const int cx = (int)(cell & 127u);
    float* dst = &out[(((size_t)(b * OCH + ch)) * NY_ + cy) * NX_ + cx];
    if (use_atomic) atomicAdd(dst, acc);
    else            *dst = acc;
}

__global__ __launch_bounds__(256) void k_gather(
        const unsigned* __restrict__ cellofs, const uint2* __restrict__ srt,
        const float* __restrict__ ctx_ws, float* __restrict__ out) {
    const int wid = __builtin_amdgcn_readfirstlane(
                        (blockIdx.x * 256 + threadIdx.x) >> 6);
    const int ch = threadIdx.x & 63;
    const unsigned K = cellofs[NCELL - 1];
    unsigned i = (unsigned)wid * TCH;
    if (i >= K) return;
    const unsigned s1 = (i + TCH < K) ? (i + TCH) : K;

    unsigned cur = srt[i].x >> 14;
    float acc = 0.f;
    bool flushed = false;

    while (i + 8 <= s1) {
        uint2 r8[8]; float v8[8];
        #pragma unroll
        for (int j = 0; j < 8; ++j) r8[j] = srt[i + j];
        #pragma unroll
        for (int j = 0; j < 8; ++j)
            v8[j] = ctx_ws[(size_t)(r8[j].x & 0x3FFFu) * OCH + ch];
        #pragma unroll
        for (int j = 0; j < 8; ++j) {
            const unsigned c = r8[j].x >> 14;
            if (c != cur) {
                flush_cell(out, cur, ch, acc, !flushed);
                flushed = true;
                acc = 0.f;
                cur = c;
            }
            acc = fmaf(__uint_as_float(r8[j].y), v8[j], acc);
        }
        i += 8;
    }
    while (i < s1) {
        const uint2 rr = srt[i];
        const float vv = ctx_ws[(size_t)(rr.x & 0x3FFFu) * OCH + ch];
        const unsigned c = rr.x >> 14;
        if (c != cur) {
            flush_cell(out, cur, ch, acc, !flushed);
            flushed = true;
            acc = 0.f;
            cur = c;
        }
        acc = fmaf(__uint_as_float(rr.y), vv, acc);
        ++i;
    }
    flush_cell(out, cur, ch, acc, true);   // last run may continue next chunk
}

// ---------------------------------------------------------------------------
extern "C" void kernel_launch(void* const* d_in, const int* in_sizes, int n_in,
                              void* d_out, int out_size, void* d_ws, size_t ws_size,
                              hipStream_t stream) {
    const float* x       = (const float*)d_in[0];
    const float* rots    = (const float*)d_in[1];
    const float* trans   = (const float*)d_in[2];
    const float* intrins = (const float*)d_in[3];
    const float* depth_w = (const float*)d_in[4];
    const float* depth_b = (const float*)d_in[5];
    float* out = (float*)d_out;

    float* ws = (float*)d_ws;
    size_t off = 0;
    float* dlog     = ws + off; off += (size_t)DBN * NPIX;      // 498432
    float* ctx_ws   = ws + off; off += (size_t)NPIX * OCH;      // 540672
    float2* msum    = (float2*)(ws + off); off += (size_t)NPIX * 2; // 16896
    unsigned* cellofs = (unsigned*)(ws + off); off += NCELL;    // 32768
    unsigned short* cell16 = (unsigned short*)(ws + off);
    off += (size_t)NPTS / 2;                                    // 249216
    uint2* srt      = (uint2*)(ws + off); off += (size_t)NPTS * 2; // 996864
    // total ~9.3 MB of d_ws; all offsets 8B-aligned.

    k_conv<<<264, 256, 0, stream>>>(x, depth_w, depth_b, dlog, ctx_ws,
                                    out, cellofs);
    k_geom<<<NPTS / 256, 256, 0, stream>>>(rots, intrins, trans, dlog,
                                           msum, cell16, cellofs);
    k_scan<<<1, 1024, 0, stream>>>(cellofs);
    k_fill<<<NPTS / 256, 256, 0, stream>>>(cell16, dlog, msum, cellofs, srt);
    const int gwaves = NPTS / TCH;                 // 7788
    k_gather<<<(gwaves + 3) / 4, 256, 0, stream>>>(cellofs, srt, ctx_ws, out);
}

// Round 7
// 211.194 us; speedup vs baseline: 1.6287x; 1.1720x over previous
//
#include <hip/hip_runtime.h>
#include <hip/hip_bf16.h>
#include <math.h>

#define B_   2
#define N_   6
#define CC   256
#define OCH  64
#define DBN  59
#define FH_  16
#define FW_  44
#define PXI  (FH_*FW_)             // 704
#define NPIX (B_*N_*PXI)           // 8448
#define NPTS (B_*N_*DBN*PXI)       // 498432
#define NX_  128
#define NY_  128
#define NCELL (B_*NY_*NX_)         // 32768
#define NOUT 123
#define OUTSZ (B_*OCH*NY_*NX_)     // 2097152
#define TCH  64                    // gather chunk (slots per wave)
#define CONV_BLOCKS 264            // 132 pixel-groups x 2 output halves

#define XSTEP (703.0f/43.0f)
#define YSTEP (255.0f/15.0f)

// ---------------------------------------------------------------------------
// comb = rots @ inv(intrins): f32, non-contracted, bit-identical to the
// validated round-1..6 ordering.
// ---------------------------------------------------------------------------
__device__ __forceinline__ void comb_cam(const float* __restrict__ R,
                                         const float* __restrict__ K,
                                         float* __restrict__ out9) {
    float a = K[0], b = K[1], c = K[2];
    float d = K[3], e = K[4], f = K[5];
    float g = K[6], h = K[7], k = K[8];
    float A  =  __fsub_rn(__fmul_rn(e, k), __fmul_rn(f, h));
    float Bc = -__fsub_rn(__fmul_rn(d, k), __fmul_rn(f, g));
    float Cc =  __fsub_rn(__fmul_rn(d, h), __fmul_rn(e, g));
    float det = __fadd_rn(__fadd_rn(__fmul_rn(a, A), __fmul_rn(b, Bc)),
                          __fmul_rn(c, Cc));
    float inv[9];
    inv[0] = __fdiv_rn(A, det);
    inv[1] = __fdiv_rn(-__fsub_rn(__fmul_rn(b, k), __fmul_rn(c, h)), det);
    inv[2] = __fdiv_rn( __fsub_rn(__fmul_rn(b, f), __fmul_rn(c, e)), det);
    inv[3] = __fdiv_rn(Bc, det);
    inv[4] = __fdiv_rn( __fsub_rn(__fmul_rn(a, k), __fmul_rn(c, g)), det);
    inv[5] = __fdiv_rn(-__fsub_rn(__fmul_rn(a, f), __fmul_rn(c, d)), det);
    inv[6] = __fdiv_rn(Cc, det);
    inv[7] = __fdiv_rn(-__fsub_rn(__fmul_rn(a, h), __fmul_rn(b, g)), det);
    inv[8] = __fdiv_rn( __fsub_rn(__fmul_rn(a, e), __fmul_rn(b, d)), det);
    for (int r = 0; r < 3; ++r)
        for (int cc = 0; cc < 3; ++cc) {
            float s =        __fmul_rn(R[r*3+0], inv[0*3+cc]);
            s = __fadd_rn(s, __fmul_rn(R[r*3+1], inv[1*3+cc]));
            s = __fadd_rn(s, __fmul_rn(R[r*3+2], inv[2*3+cc]));
            out9[r*3 + cc] = s;
        }
}

// ---------------------------------------------------------------------------
// Kernel 1: LDS-staged 1x1 conv (256 -> 123) + zero-fill + softmax stats.
// Block = 64 pixels x one output-half (0: o 0..61, 1: o 62..122).
// x tile (64 KB) staged once in LDS [c][p]; wave computes 16 outputs with
// scalar weight loads. half=0 blocks also compute per-pixel (max, 1/sum)
// over the 59 depth logits via an LDS overlay of xs.
// ---------------------------------------------------------------------------
__global__ __launch_bounds__(256) void k_conv(
        const float* __restrict__ x, const float* __restrict__ wgt,
        const float* __restrict__ bias,
        float* __restrict__ dlog, float* __restrict__ ctx_ws,
        float2* __restrict__ msum,
        float* __restrict__ out, unsigned* __restrict__ cellofs) {
    __shared__ float xs[CC * 64];          // 64 KB; overlaid by featL later
    const int t = threadIdx.x;
    const int gid = blockIdx.x * 256 + t;
    const int stride = CONV_BLOCKS * 256;
    float4* o4 = (float4*)out;
    for (int i = gid; i < OUTSZ / 4; i += stride)
        o4[i] = make_float4(0.f, 0.f, 0.f, 0.f);
    for (int i = gid; i < NCELL; i += stride) cellofs[i] = 0u;

    const int pg = blockIdx.x >> 1;        // 0..131
    const int half = blockIdx.x & 1;
    const int pix0 = pg * 64;              // 704 % 64 == 0 -> no bn crossing
    const int bn = pix0 / PXI;
    const int q0 = pix0 - bn * PXI;        // multiple of 64
    const float* xb = x + (size_t)bn * CC * PXI + q0;

    // stage x tile: 16 x float4 per thread, coalesced 1KB per wave-load
    {
        const int p0 = (t & 15) * 4;
        const int cbase = t >> 4;          // 0..15
        #pragma unroll
        for (int r = 0; r < 16; ++r) {
            const int c = r * 16 + cbase;
            const float4 v = *(const float4*)(xb + (size_t)c * PXI + p0);
            *(float4*)&xs[c * 64 + p0] = v;
        }
    }
    __syncthreads();

    const int w = t >> 6;
    const int lane = t & 63;
    const int o0 = __builtin_amdgcn_readfirstlane(half * 62 + w * 16);
    const int lim = half ? NOUT : 62;

    const float* wp[16];
    #pragma unroll
    for (int kk = 0; kk < 16; ++kk) {
        int oc = o0 + kk; if (oc > NOUT - 1) oc = NOUT - 1;
        wp[kk] = wgt + (size_t)oc * CC;
    }
    float acc[16];
    #pragma unroll
    for (int kk = 0; kk < 16; ++kk) acc[kk] = 0.f;

    #pragma unroll 4
    for (int c = 0; c < CC; ++c) {
        const float xv = xs[c * 64 + lane];
        #pragma unroll
        for (int kk = 0; kk < 16; ++kk)
            acc[kk] = fmaf(xv, wp[kk][c], acc[kk]);
    }

    float av[16];
    #pragma unroll
    for (int kk = 0; kk < 16; ++kk) {
        const int o = o0 + kk;
        if (o >= lim) break;
        const float a = acc[kk] + bias[o];
        av[kk] = a;
        if (o < DBN) dlog[(size_t)o * NPIX + pix0 + lane] = a;
        else         ctx_ws[(size_t)(pix0 + lane) * OCH + (o - DBN)] = a;
    }

    // ---- softmax stats (half=0 blocks hold all 59 depth logits) ----
    __syncthreads();                       // everyone done reading xs
    if (half == 0) {
        #pragma unroll
        for (int kk = 0; kk < 16; ++kk) {
            const int o = o0 + kk;
            if (o >= lim) break;
            if (o < DBN) xs[o * 64 + lane] = av[kk];   // featL overlay
        }
    }
    __syncthreads();
    if (half == 0 && t < 64) {
        float m = -1e30f;
        #pragma unroll
        for (int d = 0; d < DBN; ++d) m = fmaxf(m, xs[d * 64 + t]);
        float s = 0.f;
        #pragma unroll
        for (int d = 0; d < DBN; ++d) s += expf(xs[d * 64 + t] - m);
        msum[pix0 + t] = make_float2(m, 1.0f / s);
    }
}

// ---------------------------------------------------------------------------
// Kernel 2: per-POINT geometry + wave-aggregated histogram.
// ---------------------------------------------------------------------------
__global__ __launch_bounds__(256) void k_geom(
        const float* __restrict__ rots, const float* __restrict__ intrins,
        const float* __restrict__ trans,
        unsigned short* __restrict__ cell16, unsigned* __restrict__ cellofs) {
    __shared__ float combs[B_ * N_ * 9];
    __shared__ float trs[B_ * N_ * 3];
    const int t = threadIdx.x;
    if (t < B_ * N_) comb_cam(rots + t * 9, intrins + t * 9, &combs[t * 9]);
    if (t < B_ * N_ * 3) trs[t] = trans[t];
    __syncthreads();

    const int pt = blockIdx.x * 256 + t;           // grid exact: 1947*256
    const int q  = pt % PXI;
    const int r  = pt / PXI;
    const int dq = r % DBN;
    const int bn = r / DBN;
    const int hq = q / FW_;
    const int wq = q - hq * FW_;
    const int bq = bn / N_;

    const float* cb = &combs[bn * 9];
    const float t0 = trs[bn*3+0], t1 = trs[bn*3+1], t2 = trs[bn*3+2];

    const float dsv = __fadd_rn(1.0f, (float)dq);
    const float xsv = __fmul_rn((float)wq, XSTEP);
    const float ysv = __fmul_rn((float)hq, YSTEP);
    const float px = __fmul_rn(xsv, dsv);
    const float py = __fmul_rn(ysv, dsv);
    const float pz = dsv;
    float gx = __fadd_rn(__fadd_rn(__fmul_rn(cb[0], px), __fmul_rn(cb[1], py)),
                         __fmul_rn(cb[2], pz));
    float gy = __fadd_rn(__fadd_rn(__fmul_rn(cb[3], px), __fmul_rn(cb[4], py)),
                         __fmul_rn(cb[5], pz));
    float gz = __fadd_rn(__fadd_rn(__fmul_rn(cb[6], px), __fmul_rn(cb[7], py)),
                         __fmul_rn(cb[8], pz));
    gx = __fadd_rn(gx, t0);
    gy = __fadd_rn(gy, t1);
    gz = __fadd_rn(gz, t2);

    const float bxv = -50.8f;
    const float lbx = __fsub_rn(bxv, 0.4f);
    const float lbz = -10.0f;
    const int cx = (int)floorf(__fdiv_rn(__fsub_rn(gx, lbx), 0.8f));
    const int cy = (int)floorf(__fdiv_rn(__fsub_rn(gy, lbx), 0.8f));
    const int cz = (int)floorf(__fdiv_rn(__fsub_rn(gz, lbz), 20.0f));

    int c = -1;
    if (cx >= 0 && cx < NX_ && cy >= 0 && cy < NY_ && cz == 0)
        c = bq * (NY_ * NX_) + cy * NX_ + cx;
    cell16[pt] = (c >= 0) ? (unsigned short)c : (unsigned short)0xFFFFu;

    const int lane = t & 63;
    unsigned long long active = __ballot(c >= 0);
    while (active) {
        const int leader = (int)__ffsll((unsigned long long)active) - 1;
        const int lc = __shfl(c, leader);
        const unsigned long long same = __ballot(c == lc);
        if (lane == leader)
            atomicAdd(&cellofs[lc], (unsigned)__popcll(same));
        active &= ~same;
    }
}

// ---------------------------------------------------------------------------
// Kernel 3: in-place exclusive scan of cellofs[32768]. One block, 1024 thr.
// ---------------------------------------------------------------------------
__global__ __launch_bounds__(1024) void k_scan(unsigned* __restrict__ cellofs) {
    __shared__ unsigned lds[2][1024];
    const int t = threadIdx.x;
    uint4 u[8];
    const uint4* src4 = (const uint4*)cellofs + (size_t)t * 8;
    #pragma unroll
    for (int i = 0; i < 8; ++i) u[i] = src4[i];
    unsigned vv[32];
    unsigned run = 0;
    #pragma unroll
    for (int i = 0; i < 8; ++i) {
        vv[i*4+0] = run; run += u[i].x;
        vv[i*4+1] = run; run += u[i].y;
        vv[i*4+2] = run; run += u[i].z;
        vv[i*4+3] = run; run += u[i].w;
    }
    lds[0][t] = run;
    __syncthreads();
    int src = 0;
    for (int off = 1; off < 1024; off <<= 1) {
        unsigned val = lds[src][t];
        if (t >= off) val += lds[src][t - off];
        lds[1 - src][t] = val;
        __syncthreads();
        src = 1 - src;
    }
    const unsigned base = (t == 0) ? 0u : lds[src][t - 1];
    uint4* dst4 = (uint4*)cellofs + (size_t)t * 8;
    #pragma unroll
    for (int i = 0; i < 8; ++i) {
        uint4 w;
        w.x = base + vv[i*4+0];
        w.y = base + vv[i*4+1];
        w.z = base + vv[i*4+2];
        w.w = base + vv[i*4+3];
        dst4[i] = w;
    }
}

// ---------------------------------------------------------------------------
// Kernel 4: fill CSR slots. Wave-aggregated cursor atomics; weight =
// exp(dlog - m) * invs. srt[slot] = {(cell<<14)|pix, bits(w)}.
// ---------------------------------------------------------------------------
__global__ __launch_bounds__(256) void k_fill(
        const unsigned short* __restrict__ cell16,
        const float* __restrict__ dlog, const float2* __restrict__ msum,
        unsigned* __restrict__ cellofs, uint2* __restrict__ srt) {
    const int pt = blockIdx.x * 256 + threadIdx.x;
    const unsigned cc = cell16[pt];
    const int c = (cc == 0xFFFFu) ? -1 : (int)cc;
    const int lane = threadIdx.x & 63;

    unsigned slot = 0;
    unsigned long long active = __ballot(c >= 0);
    while (active) {
        const int leader = (int)__ffsll((unsigned long long)active) - 1;
        const int lc = __shfl(c, leader);
        const unsigned long long same = __ballot(c == lc);
        unsigned b0 = 0;
        if (lane == leader)
            b0 = atomicAdd(&cellofs[lc], (unsigned)__popcll(same));
        b0 = __shfl(b0, leader);
        if (c == lc)
            slot = b0 + (unsigned)__popcll(same & ((1ULL << lane) - 1ULL));
        active &= ~same;
    }

    if (c >= 0) {
        const int q  = pt % PXI;
        const int r  = pt / PXI;
        const int dq = r % DBN;
        const int bn = r / DBN;
        const int pix = bn * PXI + q;
        const float2 ms = msum[pix];
        const float w = expf(dlog[(size_t)dq * NPIX + pix] - ms.x) * ms.y;
        srt[slot] = make_uint2(((unsigned)c << 14) | (unsigned)pix,
                               __float_as_uint(w));
    }
}

// ---------------------------------------------------------------------------
// Kernel 5: load-balanced chunked gather (TCH=64). wave = chunk, lane = ch.
// Interior runs plain-store; first/last run atomicAdd.
// ---------------------------------------------------------------------------
__device__ __forceinline__ void flush_cell(float* __restrict__ out, unsigned cell,
                                           int ch, float acc, bool use_atomic) {
    const int b  = (int)(cell >> 14);
    const int cy = (int)((cell >> 7) & 127u);
    const int cx = (int)(cell & 127u);
    float* dst = &out[(((size_t)(b * OCH + ch)) * NY_ + cy) * NX_ + cx];
    if (use_atomic) atomicAdd(dst, acc);
    else            *dst = acc;
}

__global__ __launch_bounds__(256) void k_gather(
        const unsigned* __restrict__ cellofs, const uint2* __restrict__ srt,
        const float* __restrict__ ctx_ws, float* __restrict__ out) {
    const int wid = __builtin_amdgcn_readfirstlane(
                        (blockIdx.x * 256 + threadIdx.x) >> 6);
    const int ch = threadIdx.x & 63;
    const unsigned K = cellofs[NCELL - 1];
    unsigned i = (unsigned)wid * TCH;
    if (i >= K) return;
    const unsigned s1 = (i + TCH < K) ? (i + TCH) : K;

    unsigned cur = srt[i].x >> 14;
    float acc = 0.f;
    bool flushed = false;

    while (i + 8 <= s1) {
        uint2 r8[8]; float v8[8];
        #pragma unroll
        for (int j = 0; j < 8; ++j) r8[j] = srt[i + j];
        #pragma unroll
        for (int j = 0; j < 8; ++j)
            v8[j] = ctx_ws[(size_t)(r8[j].x & 0x3FFFu) * OCH + ch];
        #pragma unroll
        for (int j = 0; j < 8; ++j) {
            const unsigned c = r8[j].x >> 14;
            if (c != cur) {
                flush_cell(out, cur, ch, acc, !flushed);
                flushed = true;
                acc = 0.f;
                cur = c;
            }
            acc = fmaf(__uint_as_float(r8[j].y), v8[j], acc);
        }
        i += 8;
    }
    while (i < s1) {
        const uint2 rr = srt[i];
        const float vv = ctx_ws[(size_t)(rr.x & 0x3FFFu) * OCH + ch];
        const unsigned c = rr.x >> 14;
        if (c != cur) {
            flush_cell(out, cur, ch, acc, !flushed);
            flushed = true;
            acc = 0.f;
            cur = c;
        }
        acc = fmaf(__uint_as_float(rr.y), vv, acc);
        ++i;
    }
    flush_cell(out, cur, ch, acc, true);   // last run may continue next chunk
}

// ---------------------------------------------------------------------------
extern "C" void kernel_launch(void* const* d_in, const int* in_sizes, int n_in,
                              void* d_out, int out_size, void* d_ws, size_t ws_size,
                              hipStream_t stream) {
    const float* x       = (const float*)d_in[0];
    const float* rots    = (const float*)d_in[1];
    const float* trans   = (const float*)d_in[2];
    const float* intrins = (const float*)d_in[3];
    const float* depth_w = (const float*)d_in[4];
    const float* depth_b = (const float*)d_in[5];
    float* out = (float*)d_out;

    float* ws = (float*)d_ws;
    size_t off = 0;
    float* dlog     = ws + off; off += (size_t)DBN * NPIX;      // 498432
    float* ctx_ws   = ws + off; off += (size_t)NPIX * OCH;      // 540672
    float2* msum    = (float2*)(ws + off); off += (size_t)NPIX * 2; // 16896
    unsigned* cellofs = (unsigned*)(ws + off); off += NCELL;    // 32768
    unsigned short* cell16 = (unsigned short*)(ws + off);
    off += (size_t)NPTS / 2;                                    // 249216
    uint2* srt      = (uint2*)(ws + off); off += (size_t)NPTS * 2; // 996864
    // total ~9.3 MB of d_ws; all offsets 8B-aligned.

    k_conv<<<CONV_BLOCKS, 256, 0, stream>>>(x, depth_w, depth_b, dlog, ctx_ws,
                                            msum, out, cellofs);
    k_geom<<<NPTS / 256, 256, 0, stream>>>(rots, intrins, trans,
                                           cell16, cellofs);
    k_scan<<<1, 1024, 0, stream>>>(cellofs);
    k_fill<<<NPTS / 256, 256, 0, stream>>>(cell16, dlog, msum, cellofs, srt);
    const int gwaves = NPTS / TCH;                 // 7788
    k_gather<<<(gwaves + 3) / 4, 256, 0, stream>>>(cellofs, srt, ctx_ws, out);
}

// Round 9
// 178.265 us; speedup vs baseline: 1.9295x; 1.1847x over previous
//
#include <hip/hip_runtime.h>
#include <hip/hip_bf16.h>
#include <math.h>

#define B_   2
#define N_   6
#define CC   256
#define OCH  64
#define DBN  59
#define FH_  16
#define FW_  44
#define PXI  (FH_*FW_)             // 704
#define NPIX (B_*N_*PXI)           // 8448
#define NPTS (B_*N_*DBN*PXI)       // 498432
#define NX_  128
#define NY_  128
#define NCELL (B_*NY_*NX_)         // 32768
#define NOUT 123
#define OUTSZ (B_*OCH*NY_*NX_)     // 2097152
#define TCH  32                    // gather chunk (slots per wave)
#define CONV_BLOCKS 264            // 132 pixel-groups x 2 output halves

#define XSTEP (703.0f/43.0f)
#define YSTEP (255.0f/15.0f)

// ---------------------------------------------------------------------------
// comb = rots @ inv(intrins): f32, non-contracted, bit-identical to the
// validated round-1..7 ordering.
// ---------------------------------------------------------------------------
__device__ __forceinline__ void comb_cam(const float* __restrict__ R,
                                         const float* __restrict__ K,
                                         float* __restrict__ out9) {
    float a = K[0], b = K[1], c = K[2];
    float d = K[3], e = K[4], f = K[5];
    float g = K[6], h = K[7], k = K[8];
    float A  =  __fsub_rn(__fmul_rn(e, k), __fmul_rn(f, h));
    float Bc = -__fsub_rn(__fmul_rn(d, k), __fmul_rn(f, g));
    float Cc =  __fsub_rn(__fmul_rn(d, h), __fmul_rn(e, g));
    float det = __fadd_rn(__fadd_rn(__fmul_rn(a, A), __fmul_rn(b, Bc)),
                          __fmul_rn(c, Cc));
    float inv[9];
    inv[0] = __fdiv_rn(A, det);
    inv[1] = __fdiv_rn(-__fsub_rn(__fmul_rn(b, k), __fmul_rn(c, h)), det);
    inv[2] = __fdiv_rn( __fsub_rn(__fmul_rn(b, f), __fmul_rn(c, e)), det);
    inv[3] = __fdiv_rn(Bc, det);
    inv[4] = __fdiv_rn( __fsub_rn(__fmul_rn(a, k), __fmul_rn(c, g)), det);
    inv[5] = __fdiv_rn(-__fsub_rn(__fmul_rn(a, f), __fmul_rn(c, d)), det);
    inv[6] = __fdiv_rn(Cc, det);
    inv[7] = __fdiv_rn(-__fsub_rn(__fmul_rn(a, h), __fmul_rn(b, g)), det);
    inv[8] = __fdiv_rn( __fsub_rn(__fmul_rn(a, e), __fmul_rn(b, d)), det);
    for (int r = 0; r < 3; ++r)
        for (int cc = 0; cc < 3; ++cc) {
            float s =        __fmul_rn(R[r*3+0], inv[0*3+cc]);
            s = __fadd_rn(s, __fmul_rn(R[r*3+1], inv[1*3+cc]));
            s = __fadd_rn(s, __fmul_rn(R[r*3+2], inv[2*3+cc]));
            out9[r*3 + cc] = s;
        }
}

// ---------------------------------------------------------------------------
// Kernel 1: LDS-staged 1x1 conv (256 -> 123) + cellofs zero + softmax stats.
// zfill (optional): zero-filled float4 region (used for `out` in fallback).
// ---------------------------------------------------------------------------
__global__ __launch_bounds__(256) void k_conv(
        const float* __restrict__ x, const float* __restrict__ wgt,
        const float* __restrict__ bias,
        float* __restrict__ dlog, float* __restrict__ ctx_ws,
        float2* __restrict__ msum, unsigned* __restrict__ cellofs,
        float4* __restrict__ zfill) {
    __shared__ float xs[CC * 64];          // 64 KB; overlaid by featL later
    const int t = threadIdx.x;
    const int gid = blockIdx.x * 256 + t;
    const int stride = CONV_BLOCKS * 256;
    for (int i = gid; i < NCELL; i += stride) cellofs[i] = 0u;
    if (zfill) {
        for (int i = gid; i < OUTSZ / 4; i += stride)
            zfill[i] = make_float4(0.f, 0.f, 0.f, 0.f);
    }

    const int pg = blockIdx.x >> 1;        // 0..131
    const int half = blockIdx.x & 1;
    const int pix0 = pg * 64;              // 704 % 64 == 0 -> no bn crossing
    const int bn = pix0 / PXI;
    const int q0 = pix0 - bn * PXI;        // multiple of 64
    const float* xb = x + (size_t)bn * CC * PXI + q0;

    // stage x tile: 16 x float4 per thread, coalesced
    {
        const int p0 = (t & 15) * 4;
        const int cbase = t >> 4;          // 0..15
        #pragma unroll
        for (int r = 0; r < 16; ++r) {
            const int c = r * 16 + cbase;
            const float4 v = *(const float4*)(xb + (size_t)c * PXI + p0);
            *(float4*)&xs[c * 64 + p0] = v;
        }
    }
    __syncthreads();

    const int w = t >> 6;
    const int lane = t & 63;
    const int o0 = __builtin_amdgcn_readfirstlane(half * 62 + w * 16);
    const int lim = half ? NOUT : 62;

    const float* wp[16];
    #pragma unroll
    for (int kk = 0; kk < 16; ++kk) {
        int oc = o0 + kk; if (oc > NOUT - 1) oc = NOUT - 1;
        wp[kk] = wgt + (size_t)oc * CC;
    }
    float acc[16];
    #pragma unroll
    for (int kk = 0; kk < 16; ++kk) acc[kk] = 0.f;

    #pragma unroll 4
    for (int c = 0; c < CC; ++c) {
        const float xv = xs[c * 64 + lane];
        #pragma unroll
        for (int kk = 0; kk < 16; ++kk)
            acc[kk] = fmaf(xv, wp[kk][c], acc[kk]);
    }

    float av[16];
    #pragma unroll
    for (int kk = 0; kk < 16; ++kk) {
        const int o = o0 + kk;
        if (o >= lim) break;
        const float a = acc[kk] + bias[o];
        av[kk] = a;
        if (o < DBN) dlog[(size_t)o * NPIX + pix0 + lane] = a;
        else         ctx_ws[(size_t)(pix0 + lane) * OCH + (o - DBN)] = a;
    }

    // ---- softmax stats (half=0 blocks hold all 59 depth logits) ----
    __syncthreads();                       // everyone done reading xs
    if (half == 0) {
        #pragma unroll
        for (int kk = 0; kk < 16; ++kk) {
            const int o = o0 + kk;
            if (o >= lim) break;
            if (o < DBN) xs[o * 64 + lane] = av[kk];   // featL overlay
        }
    }
    __syncthreads();
    if (half == 0 && t < 64) {
        float m = -1e30f;
        #pragma unroll
        for (int d = 0; d < DBN; ++d) m = fmaxf(m, xs[d * 64 + t]);
        float s = 0.f;
        #pragma unroll
        for (int d = 0; d < DBN; ++d) s += expf(xs[d * 64 + t] - m);
        msum[pix0 + t] = make_float2(m, 1.0f / s);
    }
}

// ---------------------------------------------------------------------------
// Kernel 2: per-POINT geometry + wave-aggregated histogram.
// ---------------------------------------------------------------------------
__global__ __launch_bounds__(256) void k_geom(
        const float* __restrict__ rots, const float* __restrict__ intrins,
        const float* __restrict__ trans,
        unsigned short* __restrict__ cell16, unsigned* __restrict__ cellofs) {
    __shared__ float combs[B_ * N_ * 9];
    __shared__ float trs[B_ * N_ * 3];
    const int t = threadIdx.x;
    if (t < B_ * N_) comb_cam(rots + t * 9, intrins + t * 9, &combs[t * 9]);
    if (t < B_ * N_ * 3) trs[t] = trans[t];
    __syncthreads();

    const int pt = blockIdx.x * 256 + t;           // grid exact: 1947*256
    const int q  = pt % PXI;
    const int r  = pt / PXI;
    const int dq = r % DBN;
    const int bn = r / DBN;
    const int hq = q / FW_;
    const int wq = q - hq * FW_;
    const int bq = bn / N_;

    const float* cb = &combs[bn * 9];
    const float t0 = trs[bn*3+0], t1 = trs[bn*3+1], t2 = trs[bn*3+2];

    const float dsv = __fadd_rn(1.0f, (float)dq);
    const float xsv = __fmul_rn((float)wq, XSTEP);
    const float ysv = __fmul_rn((float)hq, YSTEP);
    const float px = __fmul_rn(xsv, dsv);
    const float py = __fmul_rn(ysv, dsv);
    const float pz = dsv;
    float gx = __fadd_rn(__fadd_rn(__fmul_rn(cb[0], px), __fmul_rn(cb[1], py)),
                         __fmul_rn(cb[2], pz));
    float gy = __fadd_rn(__fadd_rn(__fmul_rn(cb[3], px), __fmul_rn(cb[4], py)),
                         __fmul_rn(cb[5], pz));
    float gz = __fadd_rn(__fadd_rn(__fmul_rn(cb[6], px), __fmul_rn(cb[7], py)),
                         __fmul_rn(cb[8], pz));
    gx = __fadd_rn(gx, t0);
    gy = __fadd_rn(gy, t1);
    gz = __fadd_rn(gz, t2);

    const float bxv = -50.8f;
    const float lbx = __fsub_rn(bxv, 0.4f);
    const float lbz = -10.0f;
    const int cx = (int)floorf(__fdiv_rn(__fsub_rn(gx, lbx), 0.8f));
    const int cy = (int)floorf(__fdiv_rn(__fsub_rn(gy, lbx), 0.8f));
    const int cz = (int)floorf(__fdiv_rn(__fsub_rn(gz, lbz), 20.0f));

    int c = -1;
    if (cx >= 0 && cx < NX_ && cy >= 0 && cy < NY_ && cz == 0)
        c = bq * (NY_ * NX_) + cy * NX_ + cx;
    cell16[pt] = (c >= 0) ? (unsigned short)c : (unsigned short)0xFFFFu;

    const int lane = t & 63;
    unsigned long long active = __ballot(c >= 0);
    while (active) {
        const int leader = (int)__ffsll((unsigned long long)active) - 1;
        const int lc = __shfl(c, leader);
        const unsigned long long same = __ballot(c == lc);
        if (lane == leader)
            atomicAdd(&cellofs[lc], (unsigned)__popcll(same));
        active &= ~same;
    }
}

// ---------------------------------------------------------------------------
// Kernel 3: in-place exclusive scan of cellofs[32768]. One block, 1024 thr.
// ---------------------------------------------------------------------------
__global__ __launch_bounds__(1024) void k_scan(unsigned* __restrict__ cellofs) {
    __shared__ unsigned lds[2][1024];
    const int t = threadIdx.x;
    uint4 u[8];
    const uint4* src4 = (const uint4*)cellofs + (size_t)t * 8;
    #pragma unroll
    for (int i = 0; i < 8; ++i) u[i] = src4[i];
    unsigned vv[32];
    unsigned run = 0;
    #pragma unroll
    for (int i = 0; i < 8; ++i) {
        vv[i*4+0] = run; run += u[i].x;
        vv[i*4+1] = run; run += u[i].y;
        vv[i*4+2] = run; run += u[i].z;
        vv[i*4+3] = run; run += u[i].w;
    }
    lds[0][t] = run;
    __syncthreads();
    int src = 0;
    for (int off = 1; off < 1024; off <<= 1) {
        unsigned val = lds[src][t];
        if (t >= off) val += lds[src][t - off];
        lds[1 - src][t] = val;
        __syncthreads();
        src = 1 - src;
    }
    const unsigned base = (t == 0) ? 0u : lds[src][t - 1];
    uint4* dst4 = (uint4*)cellofs + (size_t)t * 8;
    #pragma unroll
    for (int i = 0; i < 8; ++i) {
        uint4 w;
        w.x = base + vv[i*4+0];
        w.y = base + vv[i*4+1];
        w.z = base + vv[i*4+2];
        w.w = base + vv[i*4+3];
        dst4[i] = w;
    }
}

// ---------------------------------------------------------------------------
// Kernel 4: fill CSR slots. Wave-aggregated cursor atomics; weight =
// exp(dlog - m) * invs. srt[slot] = {(cell<<14)|pix, bits(w)}.
// ---------------------------------------------------------------------------
__global__ __launch_bounds__(256) void k_fill(
        const unsigned short* __restrict__ cell16,
        const float* __restrict__ dlog, const float2* __restrict__ msum,
        unsigned* __restrict__ cellofs, uint2* __restrict__ srt) {
    const int pt = blockIdx.x * 256 + threadIdx.x;
    const unsigned cc = cell16[pt];
    const int c = (cc == 0xFFFFu) ? -1 : (int)cc;
    const int lane = threadIdx.x & 63;

    unsigned slot = 0;
    unsigned long long active = __ballot(c >= 0);
    while (active) {
        const int leader = (int)__ffsll((unsigned long long)active) - 1;
        const int lc = __shfl(c, leader);
        const unsigned long long same = __ballot(c == lc);
        unsigned b0 = 0;
        if (lane == leader)
            b0 = atomicAdd(&cellofs[lc], (unsigned)__popcll(same));
        b0 = __shfl(b0, leader);
        if (c == lc)
            slot = b0 + (unsigned)__popcll(same & ((1ULL << lane) - 1ULL));
        active &= ~same;
    }

    if (c >= 0) {
        const int q  = pt % PXI;
        const int r  = pt / PXI;
        const int dq = r % DBN;
        const int bn = r / DBN;
        const int pix = bn * PXI + q;
        const float2 ms = msum[pix];
        const float w = expf(dlog[(size_t)dq * NPIX + pix] - ms.x) * ms.y;
        srt[slot] = make_uint2(((unsigned)c << 14) | (unsigned)pix,
                               __float_as_uint(w));
    }
}

// ---------------------------------------------------------------------------
// Kernel 5: chunked gather. wave = TCH-slot chunk, lane = channel.
// Interior runs plain-store; first/last run of the chunk atomicAdd.
// MODE 0: dst = tmp[cell][64]  (contiguous 256B flushes; tmp pre-zeroed)
// MODE 1: dst = out[b][ch][y][x] (strided flushes; out pre-zeroed) -- fallback
// ---------------------------------------------------------------------------
template <int MODE>
__device__ __forceinline__ void flush_cell(float* __restrict__ dst, unsigned cell,
                                           int ch, float acc, bool use_atomic) {
    float* p;
    if (MODE == 0) {
        p = &dst[((size_t)cell << 6) + ch];
    } else {
        const int b  = (int)(cell >> 14);
        const int cy = (int)((cell >> 7) & 127u);
        const int cx = (int)(cell & 127u);
        p = &dst[(((size_t)(b * OCH + ch)) * NY_ + cy) * NX_ + cx];
    }
    if (use_atomic) atomicAdd(p, acc);
    else            *p = acc;
}

template <int MODE>
__global__ __launch_bounds__(256) void k_gather(
        const unsigned* __restrict__ cellofs, const uint2* __restrict__ srt,
        const float* __restrict__ ctx_ws, float* __restrict__ dst) {
    const int wid = __builtin_amdgcn_readfirstlane(
                        (blockIdx.x * 256 + threadIdx.x) >> 6);
    const int ch = threadIdx.x & 63;
    const unsigned K = cellofs[NCELL - 1];
    unsigned i = (unsigned)wid * TCH;
    if (i >= K) return;
    const unsigned s1 = (i + TCH < K) ? (i + TCH) : K;

    unsigned cur = srt[i].x >> 14;
    float acc = 0.f;
    bool flushed = false;

    while (i + 8 <= s1) {
        uint2 r8[8]; float v8[8];
        #pragma unroll
        for (int j = 0; j < 8; ++j) r8[j] = srt[i + j];
        #pragma unroll
        for (int j = 0; j < 8; ++j)
            v8[j] = ctx_ws[(size_t)(r8[j].x & 0x3FFFu) * OCH + ch];
        #pragma unroll
        for (int j = 0; j < 8; ++j) {
            const unsigned c = r8[j].x >> 14;
            if (c != cur) {
                flush_cell<MODE>(dst, cur, ch, acc, !flushed);
                flushed = true;
                acc = 0.f;
                cur = c;
            }
            acc = fmaf(__uint_as_float(r8[j].y), v8[j], acc);
        }
        i += 8;
    }
    while (i < s1) {
        const uint2 rr = srt[i];
        const float vv = ctx_ws[(size_t)(rr.x & 0x3FFFu) * OCH + ch];
        const unsigned c = rr.x >> 14;
        if (c != cur) {
            flush_cell<MODE>(dst, cur, ch, acc, !flushed);
            flushed = true;
            acc = 0.f;
            cur = c;
        }
        acc = fmaf(__uint_as_float(rr.y), vv, acc);
        ++i;
    }
    flush_cell<MODE>(dst, cur, ch, acc, true);  // run may continue next chunk
}

// ---------------------------------------------------------------------------
// Kernel 6 (MODE-0 path): transpose tmp[b*16384+cell][ch] -> out[b][ch][cell].
// 64x64 tiles via LDS; all global reads/writes coalesced 256B.
// ---------------------------------------------------------------------------
__global__ __launch_bounds__(256) void k_transpose(
        const float* __restrict__ tmp, float* __restrict__ out) {
    __shared__ float tile[64 * 65];
    const int t = threadIdx.x;
    const int w = t >> 6;
    const int lane = t & 63;
    const int b = blockIdx.x >> 8;          // 0..1
    const int c0 = (blockIdx.x & 255) * 64; // cell base

    #pragma unroll
    for (int r = 0; r < 16; ++r) {
        const int row = r * 4 + w;          // cell_local
        const float v = tmp[((size_t)(b * (NY_ * NX_) + c0 + row) << 6) + lane];
        tile[lane * 65 + row] = v;          // [ch][cell_local]
    }
    __syncthreads();
    #pragma unroll
    for (int r = 0; r < 16; ++r) {
        const int chv = r * 4 + w;
        out[((size_t)(b * OCH + chv) * (NY_ * NX_)) + c0 + lane] =
            tile[chv * 65 + lane];
    }
}

// ---------------------------------------------------------------------------
extern "C" void kernel_launch(void* const* d_in, const int* in_sizes, int n_in,
                              void* d_out, int out_size, void* d_ws, size_t ws_size,
                              hipStream_t stream) {
    const float* x       = (const float*)d_in[0];
    const float* rots    = (const float*)d_in[1];
    const float* trans   = (const float*)d_in[2];
    const float* intrins = (const float*)d_in[3];
    const float* depth_w = (const float*)d_in[4];
    const float* depth_b = (const float*)d_in[5];
    float* out = (float*)d_out;
    float* ws = (float*)d_ws;

    const int gblocks = (NPTS / TCH + 3) / 4;      // 3894

    // Bytes needed by the tmp-gather path:
    //   tmp 8 MB (aliases dlog/cell16/msum) + ctx 2162688 + cellofs 131072
    //   + srt 3987456 = 14,669,824
    const size_t NEED_TMP_PATH = 14669824;

    if (ws_size >= NEED_TMP_PATH) {
        // ---- tmp path: gather into [cell][64], then coalesced transpose ----
        float* tmp      = ws;                               // [0, 8MB)
        float* dlog     = ws;                               // [0, 1.90MB)
        unsigned short* cell16 = (unsigned short*)(ws + 524288);   // [2,2.95MB)
        float2* msum    = (float2*)(ws + 786432);           // [3, 3.07MB)
        float* ctx_ws   = ws + 2097152;                     // [8, 10.06MB)
        unsigned* cellofs = (unsigned*)(ws + 2637824);      // 128 KB
        uint2* srt      = (uint2*)(ws + 2670592);           // 3.99 MB

        k_conv<<<CONV_BLOCKS, 256, 0, stream>>>(x, depth_w, depth_b, dlog,
                                                ctx_ws, msum, cellofs, nullptr);
        k_geom<<<NPTS / 256, 256, 0, stream>>>(rots, intrins, trans,
                                               cell16, cellofs);
        k_scan<<<1, 1024, 0, stream>>>(cellofs);
        k_fill<<<NPTS / 256, 256, 0, stream>>>(cell16, dlog, msum, cellofs, srt);
        hipMemsetAsync(tmp, 0, (size_t)NCELL * OCH * sizeof(float), stream);
        k_gather<0><<<gblocks, 256, 0, stream>>>(cellofs, srt, ctx_ws, tmp);
        k_transpose<<<512, 256, 0, stream>>>(tmp, out);
    } else {
        // ---- fallback: round-7 layout (9.34 MB), gather straight into out ----
        float* dlog     = ws;                               // 498432 f
        float* ctx_ws   = ws + 498432;                      // 540672 f
        float2* msum    = (float2*)(ws + 1039104);          // 16896 f
        unsigned* cellofs = (unsigned*)(ws + 1056000);      // 32768 u32
        unsigned short* cell16 = (unsigned short*)(ws + 1088768); // 249216 f
        uint2* srt      = (uint2*)(ws + 1337984);           // 996864 f

        k_conv<<<CONV_BLOCKS, 256, 0, stream>>>(x, depth_w, depth_b, dlog,
                                                ctx_ws, msum, cellofs,
                                                (float4*)out);
        k_geom<<<NPTS / 256, 256, 0, stream>>>(rots, intrins, trans,
                                               cell16, cellofs);
        k_scan<<<1, 1024, 0, stream>>>(cellofs);
        k_fill<<<NPTS / 256, 256, 0, stream>>>(cell16, dlog, msum, cellofs, srt);
        k_gather<1><<<gblocks, 256, 0, stream>>>(cellofs, srt, ctx_ws, out);
    }
}

// Round 10
// 175.260 us; speedup vs baseline: 1.9626x; 1.0171x over previous
//
#include <hip/hip_runtime.h>
#include <hip/hip_bf16.h>
#include <math.h>

#define B_   2
#define N_   6
#define CC   256
#define OCH  64
#define DBN  59
#define FH_  16
#define FW_  44
#define PXI  (FH_*FW_)             // 704
#define NPIX (B_*N_*PXI)           // 8448
#define NPTS (B_*N_*DBN*PXI)       // 498432
#define NX_  128
#define NY_  128
#define NCELL (B_*NY_*NX_)         // 32768
#define NOUT 123
#define OUTSZ (B_*OCH*NY_*NX_)     // 2097152
#define TCH  32                    // gather chunk (slots per wave)

#define XSTEP (703.0f/43.0f)
#define YSTEP (255.0f/15.0f)

// ---------------------------------------------------------------------------
// comb = rots @ inv(intrins): f32, non-contracted, bit-identical to the
// validated round-1..9 ordering.
// ---------------------------------------------------------------------------
__device__ __forceinline__ void comb_cam(const float* __restrict__ R,
                                         const float* __restrict__ K,
                                         float* __restrict__ out9) {
    float a = K[0], b = K[1], c = K[2];
    float d = K[3], e = K[4], f = K[5];
    float g = K[6], h = K[7], k = K[8];
    float A  =  __fsub_rn(__fmul_rn(e, k), __fmul_rn(f, h));
    float Bc = -__fsub_rn(__fmul_rn(d, k), __fmul_rn(f, g));
    float Cc =  __fsub_rn(__fmul_rn(d, h), __fmul_rn(e, g));
    float det = __fadd_rn(__fadd_rn(__fmul_rn(a, A), __fmul_rn(b, Bc)),
                          __fmul_rn(c, Cc));
    float inv[9];
    inv[0] = __fdiv_rn(A, det);
    inv[1] = __fdiv_rn(-__fsub_rn(__fmul_rn(b, k), __fmul_rn(c, h)), det);
    inv[2] = __fdiv_rn( __fsub_rn(__fmul_rn(b, f), __fmul_rn(c, e)), det);
    inv[3] = __fdiv_rn(Bc, det);
    inv[4] = __fdiv_rn( __fsub_rn(__fmul_rn(a, k), __fmul_rn(c, g)), det);
    inv[5] = __fdiv_rn(-__fsub_rn(__fmul_rn(a, f), __fmul_rn(c, d)), det);
    inv[6] = __fdiv_rn(Cc, det);
    inv[7] = __fdiv_rn(-__fsub_rn(__fmul_rn(a, h), __fmul_rn(b, g)), det);
    inv[8] = __fdiv_rn( __fsub_rn(__fmul_rn(a, e), __fmul_rn(b, d)), det);
    for (int r = 0; r < 3; ++r)
        for (int cc = 0; cc < 3; ++cc) {
            float s =        __fmul_rn(R[r*3+0], inv[0*3+cc]);
            s = __fadd_rn(s, __fmul_rn(R[r*3+1], inv[1*3+cc]));
            s = __fadd_rn(s, __fmul_rn(R[r*3+2], inv[2*3+cc]));
            out9[r*3 + cc] = s;
        }
}

// ---------------------------------------------------------------------------
// Kernel 1a (split-K path): partial conv. Block = (pg, half, k-chunk).
// Stages a KC x 64 x-tile in LDS, computes 16 outputs/wave over KC channels,
// writes bias-free partials part[k][o][pix]. Also zero-fills cellofs.
// ---------------------------------------------------------------------------
template <int NK>
__global__ __launch_bounds__(256) void k_conv_split(
        const float* __restrict__ x, const float* __restrict__ wgt,
        float* __restrict__ parts, unsigned* __restrict__ cellofs) {
    constexpr int KC = CC / NK;            // channels per chunk
    __shared__ float xs[KC * 64];
    const int t = threadIdx.x;
    const int gid = blockIdx.x * 256 + t;
    const int stride = gridDim.x * 256;
    for (int i = gid; i < NCELL; i += stride) cellofs[i] = 0u;

    const int kc   = blockIdx.x % NK;
    const int half = (blockIdx.x / NK) & 1;
    const int pg   = blockIdx.x / (2 * NK);          // 0..131
    const int pix0 = pg * 64;              // 704 % 64 == 0 -> no bn crossing
    const int bn = pix0 / PXI;
    const int q0 = pix0 - bn * PXI;
    const float* xb = x + (size_t)bn * CC * PXI + (size_t)(kc * KC) * PXI + q0;

    // stage x tile: KC/16 x float4 per thread, coalesced
    {
        const int p0 = (t & 15) * 4;
        const int cbase = t >> 4;          // 0..15
        #pragma unroll
        for (int r = 0; r < KC / 16; ++r) {
            const int c = r * 16 + cbase;
            const float4 v = *(const float4*)(xb + (size_t)c * PXI + p0);
            *(float4*)&xs[c * 64 + p0] = v;
        }
    }
    __syncthreads();

    const int w = t >> 6;
    const int lane = t & 63;
    const int o0 = __builtin_amdgcn_readfirstlane(half * 62 + w * 16);
    const int lim = half ? NOUT : 62;

    const float* wp[16];
    #pragma unroll
    for (int kk = 0; kk < 16; ++kk) {
        int oc = o0 + kk; if (oc > NOUT - 1) oc = NOUT - 1;
        wp[kk] = wgt + (size_t)oc * CC + kc * KC;
    }
    float acc[16];
    #pragma unroll
    for (int kk = 0; kk < 16; ++kk) acc[kk] = 0.f;

    #pragma unroll 4
    for (int c = 0; c < KC; ++c) {
        const float xv = xs[c * 64 + lane];
        #pragma unroll
        for (int kk = 0; kk < 16; ++kk)
            acc[kk] = fmaf(xv, wp[kk][c], acc[kk]);
    }

    #pragma unroll
    for (int kk = 0; kk < 16; ++kk) {
        const int o = o0 + kk;
        if (o >= lim) break;
        parts[((size_t)kc * NOUT + o) * NPIX + pix0 + lane] = acc[kk];
    }
}

// ---------------------------------------------------------------------------
// Kernel 1b (split-K path): reduce partials (+bias), write dlog (o-major),
// ctx (pixel-major via LDS transpose), msum softmax stats.
// 132 blocks x 256 thr; block = 64 pixels; wave w handles o = w*31..w*31+30.
// ---------------------------------------------------------------------------
template <int NK>
__global__ __launch_bounds__(256) void k_reduce(
        const float* __restrict__ parts, const float* __restrict__ bias,
        float* __restrict__ dlog, float* __restrict__ ctx_ws,
        float2* __restrict__ msum) {
    __shared__ float lds[NOUT * 65];
    const int t = threadIdx.x;
    const int w = t >> 6;
    const int lane = t & 63;
    const int pix0 = blockIdx.x * 64;

    #pragma unroll
    for (int j = 0; j < 31; ++j) {
        const int o = w * 31 + j;
        if (o >= NOUT) break;
        float s = parts[(size_t)o * NPIX + pix0 + lane];
        #pragma unroll
        for (int k = 1; k < NK; ++k)
            s += parts[((size_t)k * NOUT + o) * NPIX + pix0 + lane];
        s += bias[o];
        lds[o * 65 + lane] = s;
        if (o < DBN) dlog[(size_t)o * NPIX + pix0 + lane] = s;
    }
    __syncthreads();

    if (t < 64) {
        float m = -1e30f;
        #pragma unroll
        for (int d = 0; d < DBN; ++d) m = fmaxf(m, lds[d * 65 + t]);
        float s = 0.f;
        #pragma unroll
        for (int d = 0; d < DBN; ++d) s += expf(lds[d * 65 + t] - m);
        msum[pix0 + t] = make_float2(m, 1.0f / s);
    }

    const int ch = t & 63;
    const int pq = t >> 6;
    #pragma unroll
    for (int px = pq; px < 64; px += 4)
        ctx_ws[(size_t)(pix0 + px) * OCH + ch] = lds[(DBN + ch) * 65 + px];
}

// ---------------------------------------------------------------------------
// Kernel 1-legacy (ws too small for partials): round-9 monolithic conv.
// ---------------------------------------------------------------------------
__global__ __launch_bounds__(256) void k_conv_mono(
        const float* __restrict__ x, const float* __restrict__ wgt,
        const float* __restrict__ bias,
        float* __restrict__ dlog, float* __restrict__ ctx_ws,
        float2* __restrict__ msum, unsigned* __restrict__ cellofs) {
    __shared__ float xs[CC * 64];
    const int t = threadIdx.x;
    const int gid = blockIdx.x * 256 + t;
    const int stride = gridDim.x * 256;
    for (int i = gid; i < NCELL; i += stride) cellofs[i] = 0u;

    const int pg = blockIdx.x >> 1;
    const int half = blockIdx.x & 1;
    const int pix0 = pg * 64;
    const int bn = pix0 / PXI;
    const int q0 = pix0 - bn * PXI;
    const float* xb = x + (size_t)bn * CC * PXI + q0;

    {
        const int p0 = (t & 15) * 4;
        const int cbase = t >> 4;
        #pragma unroll
        for (int r = 0; r < 16; ++r) {
            const int c = r * 16 + cbase;
            const float4 v = *(const float4*)(xb + (size_t)c * PXI + p0);
            *(float4*)&xs[c * 64 + p0] = v;
        }
    }
    __syncthreads();

    const int w = t >> 6;
    const int lane = t & 63;
    const int o0 = __builtin_amdgcn_readfirstlane(half * 62 + w * 16);
    const int lim = half ? NOUT : 62;

    const float* wp[16];
    #pragma unroll
    for (int kk = 0; kk < 16; ++kk) {
        int oc = o0 + kk; if (oc > NOUT - 1) oc = NOUT - 1;
        wp[kk] = wgt + (size_t)oc * CC;
    }
    float acc[16];
    #pragma unroll
    for (int kk = 0; kk < 16; ++kk) acc[kk] = 0.f;

    #pragma unroll 4
    for (int c = 0; c < CC; ++c) {
        const float xv = xs[c * 64 + lane];
        #pragma unroll
        for (int kk = 0; kk < 16; ++kk)
            acc[kk] = fmaf(xv, wp[kk][c], acc[kk]);
    }

    float av[16];
    #pragma unroll
    for (int kk = 0; kk < 16; ++kk) {
        const int o = o0 + kk;
        if (o >= lim) break;
        const float a = acc[kk] + bias[o];
        av[kk] = a;
        if (o < DBN) dlog[(size_t)o * NPIX + pix0 + lane] = a;
        else         ctx_ws[(size_t)(pix0 + lane) * OCH + (o - DBN)] = a;
    }

    __syncthreads();
    if (half == 0) {
        #pragma unroll
        for (int kk = 0; kk < 16; ++kk) {
            const int o = o0 + kk;
            if (o >= lim) break;
            if (o < DBN) xs[o * 64 + lane] = av[kk];
        }
    }
    __syncthreads();
    if (half == 0 && t < 64) {
        float m = -1e30f;
        #pragma unroll
        for (int d = 0; d < DBN; ++d) m = fmaxf(m, xs[d * 64 + t]);
        float s = 0.f;
        #pragma unroll
        for (int d = 0; d < DBN; ++d) s += expf(xs[d * 64 + t] - m);
        msum[pix0 + t] = make_float2(m, 1.0f / s);
    }
}

// ---------------------------------------------------------------------------
// Kernel 2: per-POINT geometry + wave-aggregated histogram.
// ---------------------------------------------------------------------------
__global__ __launch_bounds__(256) void k_geom(
        const float* __restrict__ rots, const float* __restrict__ intrins,
        const float* __restrict__ trans,
        unsigned short* __restrict__ cell16, unsigned* __restrict__ cellofs) {
    __shared__ float combs[B_ * N_ * 9];
    __shared__ float trs[B_ * N_ * 3];
    const int t = threadIdx.x;
    if (t < B_ * N_) comb_cam(rots + t * 9, intrins + t * 9, &combs[t * 9]);
    if (t < B_ * N_ * 3) trs[t] = trans[t];
    __syncthreads();

    const int pt = blockIdx.x * 256 + t;           // grid exact: 1947*256
    const int q  = pt % PXI;
    const int r  = pt / PXI;
    const int dq = r % DBN;
    const int bn = r / DBN;
    const int hq = q / FW_;
    const int wq = q - hq * FW_;
    const int bq = bn / N_;

    const float* cb = &combs[bn * 9];
    const float t0 = trs[bn*3+0], t1 = trs[bn*3+1], t2 = trs[bn*3+2];

    const float dsv = __fadd_rn(1.0f, (float)dq);
    const float xsv = __fmul_rn((float)wq, XSTEP);
    const float ysv = __fmul_rn((float)hq, YSTEP);
    const float px = __fmul_rn(xsv, dsv);
    const float py = __fmul_rn(ysv, dsv);
    const float pz = dsv;
    float gx = __fadd_rn(__fadd_rn(__fmul_rn(cb[0], px), __fmul_rn(cb[1], py)),
                         __fmul_rn(cb[2], pz));
    float gy = __fadd_rn(__fadd_rn(__fmul_rn(cb[3], px), __fmul_rn(cb[4], py)),
                         __fmul_rn(cb[5], pz));
    float gz = __fadd_rn(__fadd_rn(__fmul_rn(cb[6], px), __fmul_rn(cb[7], py)),
                         __fmul_rn(cb[8], pz));
    gx = __fadd_rn(gx, t0);
    gy = __fadd_rn(gy, t1);
    gz = __fadd_rn(gz, t2);

    const float bxv = -50.8f;
    const float lbx = __fsub_rn(bxv, 0.4f);
    const float lbz = -10.0f;
    const int cx = (int)floorf(__fdiv_rn(__fsub_rn(gx, lbx), 0.8f));
    const int cy = (int)floorf(__fdiv_rn(__fsub_rn(gy, lbx), 0.8f));
    const int cz = (int)floorf(__fdiv_rn(__fsub_rn(gz, lbz), 20.0f));

    int c = -1;
    if (cx >= 0 && cx < NX_ && cy >= 0 && cy < NY_ && cz == 0)
        c = bq * (NY_ * NX_) + cy * NX_ + cx;
    cell16[pt] = (c >= 0) ? (unsigned short)c : (unsigned short)0xFFFFu;

    const int lane = t & 63;
    unsigned long long active = __ballot(c >= 0);
    while (active) {
        const int leader = (int)__ffsll((unsigned long long)active) - 1;
        const int lc = __shfl(c, leader);
        const unsigned long long same = __ballot(c == lc);
        if (lane == leader)
            atomicAdd(&cellofs[lc], (unsigned)__popcll(same));
        active &= ~same;
    }
}

// ---------------------------------------------------------------------------
// Kernel 3: in-place exclusive scan of cellofs[32768]. One block, 1024 thr.
// ---------------------------------------------------------------------------
__global__ __launch_bounds__(1024) void k_scan(unsigned* __restrict__ cellofs) {
    __shared__ unsigned lds[2][1024];
    const int t = threadIdx.x;
    uint4 u[8];
    const uint4* src4 = (const uint4*)cellofs + (size_t)t * 8;
    #pragma unroll
    for (int i = 0; i < 8; ++i) u[i] = src4[i];
    unsigned vv[32];
    unsigned run = 0;
    #pragma unroll
    for (int i = 0; i < 8; ++i) {
        vv[i*4+0] = run; run += u[i].x;
        vv[i*4+1] = run; run += u[i].y;
        vv[i*4+2] = run; run += u[i].z;
        vv[i*4+3] = run; run += u[i].w;
    }
    lds[0][t] = run;
    __syncthreads();
    int src = 0;
    for (int off = 1; off < 1024; off <<= 1) {
        unsigned val = lds[src][t];
        if (t >= off) val += lds[src][t - off];
        lds[1 - src][t] = val;
        __syncthreads();
        src = 1 - src;
    }
    const unsigned base = (t == 0) ? 0u : lds[src][t - 1];
    uint4* dst4 = (uint4*)cellofs + (size_t)t * 8;
    #pragma unroll
    for (int i = 0; i < 8; ++i) {
        uint4 w;
        w.x = base + vv[i*4+0];
        w.y = base + vv[i*4+1];
        w.z = base + vv[i*4+2];
        w.w = base + vv[i*4+3];
        dst4[i] = w;
    }
}

// ---------------------------------------------------------------------------
// Kernel 4: fill CSR slots. Wave-aggregated cursor atomics; weight =
// exp(dlog - m) * invs. srt[slot] = {(cell<<14)|pix, bits(w)}.
// ---------------------------------------------------------------------------
__global__ __launch_bounds__(256) void k_fill(
        const unsigned short* __restrict__ cell16,
        const float* __restrict__ dlog, const float2* __restrict__ msum,
        unsigned* __restrict__ cellofs, uint2* __restrict__ srt) {
    const int pt = blockIdx.x * 256 + threadIdx.x;
    const unsigned cc = cell16[pt];
    const int c = (cc == 0xFFFFu) ? -1 : (int)cc;
    const int lane = threadIdx.x & 63;

    unsigned slot = 0;
    unsigned long long active = __ballot(c >= 0);
    while (active) {
        const int leader = (int)__ffsll((unsigned long long)active) - 1;
        const int lc = __shfl(c, leader);
        const unsigned long long same = __ballot(c == lc);
        unsigned b0 = 0;
        if (lane == leader)
            b0 = atomicAdd(&cellofs[lc], (unsigned)__popcll(same));
        b0 = __shfl(b0, leader);
        if (c == lc)
            slot = b0 + (unsigned)__popcll(same & ((1ULL << lane) - 1ULL));
        active &= ~same;
    }

    if (c >= 0) {
        const int q  = pt % PXI;
        const int r  = pt / PXI;
        const int dq = r % DBN;
        const int bn = r / DBN;
        const int pix = bn * PXI + q;
        const float2 ms = msum[pix];
        const float w = expf(dlog[(size_t)dq * NPIX + pix] - ms.x) * ms.y;
        srt[slot] = make_uint2(((unsigned)c << 14) | (unsigned)pix,
                               __float_as_uint(w));
    }
}

// ---------------------------------------------------------------------------
// Kernel 5: chunked gather into tmp[cell][64] (contiguous 256B flushes).
// ---------------------------------------------------------------------------
__device__ __forceinline__ void flush_cell(float* __restrict__ tmp, unsigned cell,
                                           int ch, float acc, bool use_atomic) {
    float* dst = &tmp[((size_t)cell << 6) + ch];
    if (use_atomic) atomicAdd(dst, acc);
    else            *dst = acc;
}

__global__ __launch_bounds__(256) void k_gather(
        const unsigned* __restrict__ cellofs, const uint2* __restrict__ srt,
        const float* __restrict__ ctx_ws, float* __restrict__ tmp) {
    const int wid = __builtin_amdgcn_readfirstlane(
                        (blockIdx.x * 256 + threadIdx.x) >> 6);
    const int ch = threadIdx.x & 63;
    const unsigned K = cellofs[NCELL - 1];
    unsigned i = (unsigned)wid * TCH;
    if (i >= K) return;
    const unsigned s1 = (i + TCH < K) ? (i + TCH) : K;

    unsigned cur = srt[i].x >> 14;
    float acc = 0.f;
    bool flushed = false;

    while (i + 8 <= s1) {
        uint2 r8[8]; float v8[8];
        #pragma unroll
        for (int j = 0; j < 8; ++j) r8[j] = srt[i + j];
        #pragma unroll
        for (int j = 0; j < 8; ++j)
            v8[j] = ctx_ws[(size_t)(r8[j].x & 0x3FFFu) * OCH + ch];
        #pragma unroll
        for (int j = 0; j < 8; ++j) {
            const unsigned c = r8[j].x >> 14;
            if (c != cur) {
                flush_cell(tmp, cur, ch, acc, !flushed);
                flushed = true;
                acc = 0.f;
                cur = c;
            }
            acc = fmaf(__uint_as_float(r8[j].y), v8[j], acc);
        }
        i += 8;
    }
    while (i < s1) {
        const uint2 rr = srt[i];
        const float vv = ctx_ws[(size_t)(rr.x & 0x3FFFu) * OCH + ch];
        const unsigned c = rr.x >> 14;
        if (c != cur) {
            flush_cell(tmp, cur, ch, acc, !flushed);
            flushed = true;
            acc = 0.f;
            cur = c;
        }
        acc = fmaf(__uint_as_float(rr.y), vv, acc);
        ++i;
    }
    flush_cell(tmp, cur, ch, acc, true);   // last run may continue next chunk
}

// ---------------------------------------------------------------------------
// Kernel 6: transpose tmp[b*16384+cell][ch] -> out[b][ch][cell].
// ---------------------------------------------------------------------------
__global__ __launch_bounds__(256) void k_transpose(
        const float* __restrict__ tmp, float* __restrict__ out) {
    __shared__ float tile[64 * 65];
    const int t = threadIdx.x;
    const int w = t >> 6;
    const int lane = t & 63;
    const int b = blockIdx.x >> 8;          // 0..1
    const int c0 = (blockIdx.x & 255) * 64; // cell base

    #pragma unroll
    for (int r = 0; r < 16; ++r) {
        const int row = r * 4 + w;          // cell_local
        const float v = tmp[((size_t)(b * (NY_ * NX_) + c0 + row) << 6) + lane];
        tile[lane * 65 + row] = v;          // [ch][cell_local]
    }
    __syncthreads();
    #pragma unroll
    for (int r = 0; r < 16; ++r) {
        const int chv = r * 4 + w;
        out[((size_t)(b * OCH + chv) * (NY_ * NX_)) + c0 + lane] =
            tile[chv * 65 + lane];
    }
}

// ---------------------------------------------------------------------------
extern "C" void kernel_launch(void* const* d_in, const int* in_sizes, int n_in,
                              void* d_out, int out_size, void* d_ws, size_t ws_size,
                              hipStream_t stream) {
    const float* x       = (const float*)d_in[0];
    const float* rots    = (const float*)d_in[1];
    const float* trans   = (const float*)d_in[2];
    const float* intrins = (const float*)d_in[3];
    const float* depth_w = (const float*)d_in[4];
    const float* depth_b = (const float*)d_in[5];
    float* out = (float*)d_out;
    float* ws = (float*)d_ws;

    // Base layout (proven fits: ws_size >= 14,669,824 from round 9):
    float* tmp      = ws;                               // [0, 8MB)
    float* dlog     = ws;                               // [0, 1.994MB)
    unsigned short* cell16 = (unsigned short*)(ws + 524288);   // [2, 2.95MB)
    float2* msum    = (float2*)(ws + 786432);           // [3, 3.067MB)
    float* ctx_ws   = ws + 2097152;                     // [8, 10.06MB)
    unsigned* cellofs = (unsigned*)(ws + 2637824);      // 128 KB
    uint2* srt      = (uint2*)(ws + 2670592);           // 3.99 MB -> 14.67MB
    float* parts    = ws + 3667456;                     // appended @14.669MB

    const size_t BASE = 14669824;
    const size_t PART1 = (size_t)NOUT * NPIX * 4;       // 4,156,416 B
    const int gblocks = (NPTS / TCH + 3) / 4;           // 3894

    // ---- conv stage ----
    if (ws_size >= BASE + 4 * PART1) {
        k_conv_split<4><<<132 * 2 * 4, 256, 0, stream>>>(x, depth_w,
                                                         parts, cellofs);
        k_reduce<4><<<132, 256, 0, stream>>>(parts, depth_b, dlog, ctx_ws,
                                             msum);
    } else if (ws_size >= BASE + 2 * PART1) {
        k_conv_split<2><<<132 * 2 * 2, 256, 0, stream>>>(x, depth_w,
                                                         parts, cellofs);
        k_reduce<2><<<132, 256, 0, stream>>>(parts, depth_b, dlog, ctx_ws,
                                             msum);
    } else {
        k_conv_mono<<<264, 256, 0, stream>>>(x, depth_w, depth_b, dlog,
                                             ctx_ws, msum, cellofs);
    }

    // ---- geometry / sort / gather / transpose (unchanged from round 9) ----
    k_geom<<<NPTS / 256, 256, 0, stream>>>(rots, intrins, trans,
                                           cell16, cellofs);
    k_scan<<<1, 1024, 0, stream>>>(cellofs);
    k_fill<<<NPTS / 256, 256, 0, stream>>>(cell16, dlog, msum, cellofs, srt);
    hipMemsetAsync(tmp, 0, (size_t)NCELL * OCH * sizeof(float), stream);
    k_gather<<<gblocks, 256, 0, stream>>>(cellofs, srt, ctx_ws, tmp);
    k_transpose<<<512, 256, 0, stream>>>(tmp, out);
}

// Round 11
// 152.744 us; speedup vs baseline: 2.2519x; 1.1474x over previous
//
#include <hip/hip_runtime.h>
#include <hip/hip_bf16.h>
#include <math.h>

#define B_   2
#define N_   6
#define CC   256
#define OCH  64
#define DBN  59
#define FH_  16
#define FW_  44
#define PXI  (FH_*FW_)             // 704
#define NPIX (B_*N_*PXI)           // 8448
#define NPTS (B_*N_*DBN*PXI)       // 498432
#define NX_  128
#define NY_  128
#define NCELL (B_*NY_*NX_)         // 32768
#define NOUT 123
#define OUTSZ (B_*OCH*NY_*NX_)     // 2097152
#define TCH  32                    // gather chunk (slots per wave)
#define NK_  4                     // conv K-split

#define XSTEP (703.0f/43.0f)
#define YSTEP (255.0f/15.0f)

// ---------------------------------------------------------------------------
// comb = rots @ inv(intrins): f32, non-contracted, bit-identical to the
// validated round-1..10 ordering.
// ---------------------------------------------------------------------------
__device__ __forceinline__ void comb_cam(const float* __restrict__ R,
                                         const float* __restrict__ K,
                                         float* __restrict__ out9) {
    float a = K[0], b = K[1], c = K[2];
    float d = K[3], e = K[4], f = K[5];
    float g = K[6], h = K[7], k = K[8];
    float A  =  __fsub_rn(__fmul_rn(e, k), __fmul_rn(f, h));
    float Bc = -__fsub_rn(__fmul_rn(d, k), __fmul_rn(f, g));
    float Cc =  __fsub_rn(__fmul_rn(d, h), __fmul_rn(e, g));
    float det = __fadd_rn(__fadd_rn(__fmul_rn(a, A), __fmul_rn(b, Bc)),
                          __fmul_rn(c, Cc));
    float inv[9];
    inv[0] = __fdiv_rn(A, det);
    inv[1] = __fdiv_rn(-__fsub_rn(__fmul_rn(b, k), __fmul_rn(c, h)), det);
    inv[2] = __fdiv_rn( __fsub_rn(__fmul_rn(b, f), __fmul_rn(c, e)), det);
    inv[3] = __fdiv_rn(Bc, det);
    inv[4] = __fdiv_rn( __fsub_rn(__fmul_rn(a, k), __fmul_rn(c, g)), det);
    inv[5] = __fdiv_rn(-__fsub_rn(__fmul_rn(a, f), __fmul_rn(c, d)), det);
    inv[6] = __fdiv_rn(Cc, det);
    inv[7] = __fdiv_rn(-__fsub_rn(__fmul_rn(a, h), __fmul_rn(b, g)), det);
    inv[8] = __fdiv_rn( __fsub_rn(__fmul_rn(a, e), __fmul_rn(b, d)), det);
    for (int r = 0; r < 3; ++r)
        for (int cc = 0; cc < 3; ++cc) {
            float s =        __fmul_rn(R[r*3+0], inv[0*3+cc]);
            s = __fadd_rn(s, __fmul_rn(R[r*3+1], inv[1*3+cc]));
            s = __fadd_rn(s, __fmul_rn(R[r*3+2], inv[2*3+cc]));
            out9[r*3 + cc] = s;
        }
}

// ---------------------------------------------------------------------------
// Geometry for one point -> cell id (or -1). Bit-identical FP to round 1..10.
// ---------------------------------------------------------------------------
__device__ __forceinline__ int geom_cell(int pt, const float* __restrict__ combs,
                                         const float* __restrict__ trs) {
    const int q  = pt % PXI;
    const int r  = pt / PXI;
    const int dq = r % DBN;
    const int bn = r / DBN;
    const int hq = q / FW_;
    const int wq = q - hq * FW_;
    const int bq = bn / N_;

    const float* cb = &combs[bn * 9];
    const float t0 = trs[bn*3+0], t1 = trs[bn*3+1], t2 = trs[bn*3+2];

    const float dsv = __fadd_rn(1.0f, (float)dq);
    const float xsv = __fmul_rn((float)wq, XSTEP);
    const float ysv = __fmul_rn((float)hq, YSTEP);
    const float px = __fmul_rn(xsv, dsv);
    const float py = __fmul_rn(ysv, dsv);
    const float pz = dsv;
    float gx = __fadd_rn(__fadd_rn(__fmul_rn(cb[0], px), __fmul_rn(cb[1], py)),
                         __fmul_rn(cb[2], pz));
    float gy = __fadd_rn(__fadd_rn(__fmul_rn(cb[3], px), __fmul_rn(cb[4], py)),
                         __fmul_rn(cb[5], pz));
    float gz = __fadd_rn(__fadd_rn(__fmul_rn(cb[6], px), __fmul_rn(cb[7], py)),
                         __fmul_rn(cb[8], pz));
    gx = __fadd_rn(gx, t0);
    gy = __fadd_rn(gy, t1);
    gz = __fadd_rn(gz, t2);

    const float bxv = -50.8f;
    const float lbx = __fsub_rn(bxv, 0.4f);
    const float lbz = -10.0f;
    const int cx = (int)floorf(__fdiv_rn(__fsub_rn(gx, lbx), 0.8f));
    const int cy = (int)floorf(__fdiv_rn(__fsub_rn(gy, lbx), 0.8f));
    const int cz = (int)floorf(__fdiv_rn(__fsub_rn(gz, lbz), 20.0f));

    if (cx >= 0 && cx < NX_ && cy >= 0 && cy < NY_ && cz == 0)
        return bq * (NY_ * NX_) + cy * NX_ + cx;
    return -1;
}

// ---------------------------------------------------------------------------
// Kernel FRONT (fused): blocks [0, 132*2*NK) do split-K conv partials;
// blocks [132*2*NK, +1947) do per-point geometry + histogram.
// Independent phases co-resident -> latency of each hides under the other.
// ---------------------------------------------------------------------------
template <int NK>
__global__ __launch_bounds__(256) void k_front(
        const float* __restrict__ x, const float* __restrict__ wgt,
        const float* __restrict__ rots, const float* __restrict__ intrins,
        const float* __restrict__ trans,
        float* __restrict__ parts, unsigned short* __restrict__ cell16,
        unsigned* __restrict__ cellofs) {
    constexpr int KC = CC / NK;
    constexpr int NCONV = 132 * 2 * NK;
    __shared__ float xs[KC * 64];
    __shared__ float combs[B_ * N_ * 9];
    __shared__ float trs[B_ * N_ * 3];
    const int t = threadIdx.x;

    if (blockIdx.x < NCONV) {
        // ---------------- conv partial phase ----------------
        const int kc   = blockIdx.x % NK;
        const int half = (blockIdx.x / NK) & 1;
        const int pg   = blockIdx.x / (2 * NK);      // 0..131
        const int pix0 = pg * 64;
        const int bn = pix0 / PXI;
        const int q0 = pix0 - bn * PXI;
        const float* xb = x + (size_t)bn * CC * PXI
                            + (size_t)(kc * KC) * PXI + q0;
        {
            const int p0 = (t & 15) * 4;
            const int cbase = t >> 4;
            #pragma unroll
            for (int r = 0; r < KC / 16; ++r) {
                const int c = r * 16 + cbase;
                const float4 v = *(const float4*)(xb + (size_t)c * PXI + p0);
                *(float4*)&xs[c * 64 + p0] = v;
            }
        }
        __syncthreads();

        const int w = t >> 6;
        const int lane = t & 63;
        const int o0 = __builtin_amdgcn_readfirstlane(half * 62 + w * 16);
        const int lim = half ? NOUT : 62;

        const float* wp[16];
        #pragma unroll
        for (int kk = 0; kk < 16; ++kk) {
            int oc = o0 + kk; if (oc > NOUT - 1) oc = NOUT - 1;
            wp[kk] = wgt + (size_t)oc * CC + kc * KC;
        }
        float acc[16];
        #pragma unroll
        for (int kk = 0; kk < 16; ++kk) acc[kk] = 0.f;

        #pragma unroll 4
        for (int c = 0; c < KC; ++c) {
            const float xv = xs[c * 64 + lane];
            #pragma unroll
            for (int kk = 0; kk < 16; ++kk)
                acc[kk] = fmaf(xv, wp[kk][c], acc[kk]);
        }
        #pragma unroll
        for (int kk = 0; kk < 16; ++kk) {
            const int o = o0 + kk;
            if (o >= lim) break;
            parts[((size_t)kc * NOUT + o) * NPIX + pix0 + lane] = acc[kk];
        }
    } else {
        // ---------------- geometry + histogram phase ----------------
        if (t < B_ * N_) comb_cam(rots + t * 9, intrins + t * 9, &combs[t * 9]);
        if (t < B_ * N_ * 3) trs[t] = trans[t];
        __syncthreads();

        const int pt = (blockIdx.x - NCONV) * 256 + t;   // < 498432 exact
        const int c = geom_cell(pt, combs, trs);
        cell16[pt] = (c >= 0) ? (unsigned short)c : (unsigned short)0xFFFFu;

        const int lane = t & 63;
        unsigned long long active = __ballot(c >= 0);
        while (active) {
            const int leader = (int)__ffsll((unsigned long long)active) - 1;
            const int lc = __shfl(c, leader);
            const unsigned long long same = __ballot(c == lc);
            if (lane == leader)
                atomicAdd(&cellofs[lc], (unsigned)__popcll(same));
            active &= ~same;
        }
    }
}

// ---------------------------------------------------------------------------
// Kernel MID (fused): block 0 = exclusive scan of cellofs (256 thr, 2-pass);
// blocks 1..132 = reduce conv partials (+bias), write dlog/ctx/msum.
// ---------------------------------------------------------------------------
template <int NK>
__global__ __launch_bounds__(256) void k_mid(
        const float* __restrict__ parts, const float* __restrict__ bias,
        unsigned* __restrict__ cellofs,
        float* __restrict__ dlog, float* __restrict__ ctx_ws,
        float2* __restrict__ msum) {
    __shared__ float lds[NOUT * 65];
    __shared__ unsigned sc[2][256];
    const int t = threadIdx.x;

    if (blockIdx.x == 0) {
        // -------- scan: 128 elems/thread, two-pass (sum, then rewrite) ------
        const uint4* s4 = (const uint4*)cellofs + (size_t)t * 32;
        unsigned run = 0;
        #pragma unroll 8
        for (int i = 0; i < 32; ++i) {
            const uint4 v = s4[i];
            run += v.x + v.y + v.z + v.w;
        }
        sc[0][t] = run;
        __syncthreads();
        int src = 0;
        for (int off = 1; off < 256; off <<= 1) {
            unsigned val = sc[src][t];
            if (t >= off) val += sc[src][t - off];
            sc[1 - src][t] = val;
            __syncthreads();
            src = 1 - src;
        }
        unsigned base = (t == 0) ? 0u : sc[src][t - 1];
        uint4* d4 = (uint4*)cellofs + (size_t)t * 32;
        #pragma unroll 8
        for (int i = 0; i < 32; ++i) {
            const uint4 v = d4[i];
            uint4 w;
            w.x = base; base += v.x;
            w.y = base; base += v.y;
            w.z = base; base += v.z;
            w.w = base; base += v.w;
            d4[i] = w;
        }
    } else {
        // -------- reduce partials ------------------------------------------
        const int w = t >> 6;
        const int lane = t & 63;
        const int pix0 = (blockIdx.x - 1) * 64;

        #pragma unroll
        for (int j = 0; j < 31; ++j) {
            const int o = w * 31 + j;
            if (o >= NOUT) break;
            float s = parts[(size_t)o * NPIX + pix0 + lane];
            #pragma unroll
            for (int k = 1; k < NK; ++k)
                s += parts[((size_t)k * NOUT + o) * NPIX + pix0 + lane];
            s += bias[o];
            lds[o * 65 + lane] = s;
            if (o < DBN) dlog[(size_t)o * NPIX + pix0 + lane] = s;
        }
        __syncthreads();

        if (t < 64) {
            float m = -1e30f;
            #pragma unroll
            for (int d = 0; d < DBN; ++d) m = fmaxf(m, lds[d * 65 + t]);
            float s = 0.f;
            #pragma unroll
            for (int d = 0; d < DBN; ++d) s += expf(lds[d * 65 + t] - m);
            msum[pix0 + t] = make_float2(m, 1.0f / s);
        }
        const int ch = t & 63;
        const int pq = t >> 6;
        #pragma unroll
        for (int px = pq; px < 64; px += 4)
            ctx_ws[(size_t)(pix0 + px) * OCH + ch] = lds[(DBN + ch) * 65 + px];
    }
}

// ---------------------------------------------------------------------------
// Kernel fill: CSR slots (wave-aggregated cursor atomics), weight =
// exp(dlog - m) * invs. Optionally grid-stride zeroes tmp (disjoint region).
// ---------------------------------------------------------------------------
__global__ __launch_bounds__(256) void k_fill(
        const unsigned short* __restrict__ cell16,
        const float* __restrict__ dlog, const float2* __restrict__ msum,
        unsigned* __restrict__ cellofs, uint2* __restrict__ srt,
        float4* __restrict__ tmpz) {
    const int gid = blockIdx.x * 256 + threadIdx.x;
    if (tmpz) {
        const int stride = (NPTS / 256) * 256;
        for (int i = gid; i < OUTSZ / 4; i += stride)
            tmpz[i] = make_float4(0.f, 0.f, 0.f, 0.f);
    }

    const int pt = gid;
    const unsigned cc = cell16[pt];
    const int c = (cc == 0xFFFFu) ? -1 : (int)cc;
    const int lane = threadIdx.x & 63;

    unsigned slot = 0;
    unsigned long long active = __ballot(c >= 0);
    while (active) {
        const int leader = (int)__ffsll((unsigned long long)active) - 1;
        const int lc = __shfl(c, leader);
        const unsigned long long same = __ballot(c == lc);
        unsigned b0 = 0;
        if (lane == leader)
            b0 = atomicAdd(&cellofs[lc], (unsigned)__popcll(same));
        b0 = __shfl(b0, leader);
        if (c == lc)
            slot = b0 + (unsigned)__popcll(same & ((1ULL << lane) - 1ULL));
        active &= ~same;
    }

    if (c >= 0) {
        const int q  = pt % PXI;
        const int r  = pt / PXI;
        const int dq = r % DBN;
        const int bn = r / DBN;
        const int pix = bn * PXI + q;
        const float2 ms = msum[pix];
        const float w = expf(dlog[(size_t)dq * NPIX + pix] - ms.x) * ms.y;
        srt[slot] = make_uint2(((unsigned)c << 14) | (unsigned)pix,
                               __float_as_uint(w));
    }
}

// ---------------------------------------------------------------------------
// Kernel gather: chunked, into tmp[cell][64] (contiguous 256B flushes).
// ---------------------------------------------------------------------------
__device__ __forceinline__ void flush_cell(float* __restrict__ tmp, unsigned cell,
                                           int ch, float acc, bool use_atomic) {
    float* dst = &tmp[((size_t)cell << 6) + ch];
    if (use_atomic) atomicAdd(dst, acc);
    else            *dst = acc;
}

__global__ __launch_bounds__(256) void k_gather(
        const unsigned* __restrict__ cellofs, const uint2* __restrict__ srt,
        const float* __restrict__ ctx_ws, float* __restrict__ tmp) {
    const int wid = __builtin_amdgcn_readfirstlane(
                        (blockIdx.x * 256 + threadIdx.x) >> 6);
    const int ch = threadIdx.x & 63;
    const unsigned K = cellofs[NCELL - 1];
    unsigned i = (unsigned)wid * TCH;
    if (i >= K) return;
    const unsigned s1 = (i + TCH < K) ? (i + TCH) : K;

    unsigned cur = srt[i].x >> 14;
    float acc = 0.f;
    bool flushed = false;

    while (i + 8 <= s1) {
        uint2 r8[8]; float v8[8];
        #pragma unroll
        for (int j = 0; j < 8; ++j) r8[j] = srt[i + j];
        #pragma unroll
        for (int j = 0; j < 8; ++j)
            v8[j] = ctx_ws[(size_t)(r8[j].x & 0x3FFFu) * OCH + ch];
        #pragma unroll
        for (int j = 0; j < 8; ++j) {
            const unsigned c = r8[j].x >> 14;
            if (c != cur) {
                flush_cell(tmp, cur, ch, acc, !flushed);
                flushed = true;
                acc = 0.f;
                cur = c;
            }
            acc = fmaf(__uint_as_float(r8[j].y), v8[j], acc);
        }
        i += 8;
    }
    while (i < s1) {
        const uint2 rr = srt[i];
        const float vv = ctx_ws[(size_t)(rr.x & 0x3FFFu) * OCH + ch];
        const unsigned c = rr.x >> 14;
        if (c != cur) {
            flush_cell(tmp, cur, ch, acc, !flushed);
            flushed = true;
            acc = 0.f;
            cur = c;
        }
        acc = fmaf(__uint_as_float(rr.y), vv, acc);
        ++i;
    }
    flush_cell(tmp, cur, ch, acc, true);   // last run may continue next chunk
}

// ---------------------------------------------------------------------------
// Kernel transpose: tmp[b*16384+cell][ch] -> out[b][ch][cell].
// ---------------------------------------------------------------------------
__global__ __launch_bounds__(256) void k_transpose(
        const float* __restrict__ tmp, float* __restrict__ out) {
    __shared__ float tile[64 * 65];
    const int t = threadIdx.x;
    const int w = t >> 6;
    const int lane = t & 63;
    const int b = blockIdx.x >> 8;
    const int c0 = (blockIdx.x & 255) * 64;

    #pragma unroll
    for (int r = 0; r < 16; ++r) {
        const int row = r * 4 + w;
        const float v = tmp[((size_t)(b * (NY_ * NX_) + c0 + row) << 6) + lane];
        tile[lane * 65 + row] = v;
    }
    __syncthreads();
    #pragma unroll
    for (int r = 0; r < 16; ++r) {
        const int chv = r * 4 + w;
        out[((size_t)(b * OCH + chv) * (NY_ * NX_)) + c0 + lane] =
            tile[chv * 65 + lane];
    }
}

// ---------------------------------------------------------------------------
// FALLBACK kernels (tier B, round-9 flow) -----------------------------------
// ---------------------------------------------------------------------------
__global__ __launch_bounds__(256) void k_conv_mono(
        const float* __restrict__ x, const float* __restrict__ wgt,
        const float* __restrict__ bias,
        float* __restrict__ dlog, float* __restrict__ ctx_ws,
        float2* __restrict__ msum, unsigned* __restrict__ cellofs) {
    __shared__ float xs[CC * 64];
    const int t = threadIdx.x;
    const int gid = blockIdx.x * 256 + t;
    const int stride = gridDim.x * 256;
    for (int i = gid; i < NCELL; i += stride) cellofs[i] = 0u;

    const int pg = blockIdx.x >> 1;
    const int half = blockIdx.x & 1;
    const int pix0 = pg * 64;
    const int bn = pix0 / PXI;
    const int q0 = pix0 - bn * PXI;
    const float* xb = x + (size_t)bn * CC * PXI + q0;

    {
        const int p0 = (t & 15) * 4;
        const int cbase = t >> 4;
        #pragma unroll
        for (int r = 0; r < 16; ++r) {
            const int c = r * 16 + cbase;
            const float4 v = *(const float4*)(xb + (size_t)c * PXI + p0);
            *(float4*)&xs[c * 64 + p0] = v;
        }
    }
    __syncthreads();

    const int w = t >> 6;
    const int lane = t & 63;
    const int o0 = __builtin_amdgcn_readfirstlane(half * 62 + w * 16);
    const int lim = half ? NOUT : 62;

    const float* wp[16];
    #pragma unroll
    for (int kk = 0; kk < 16; ++kk) {
        int oc = o0 + kk; if (oc > NOUT - 1) oc = NOUT - 1;
        wp[kk] = wgt + (size_t)oc * CC;
    }
    float acc[16];
    #pragma unroll
    for (int kk = 0; kk < 16; ++kk) acc[kk] = 0.f;

    #pragma unroll 4
    for (int c = 0; c < CC; ++c) {
        const float xv = xs[c * 64 + lane];
        #pragma unroll
        for (int kk = 0; kk < 16; ++kk)
            acc[kk] = fmaf(xv, wp[kk][c], acc[kk]);
    }

    float av[16];
    #pragma unroll
    for (int kk = 0; kk < 16; ++kk) {
        const int o = o0 + kk;
        if (o >= lim) break;
        const float a = acc[kk] + bias[o];
        av[kk] = a;
        if (o < DBN) dlog[(size_t)o * NPIX + pix0 + lane] = a;
        else         ctx_ws[(size_t)(pix0 + lane) * OCH + (o - DBN)] = a;
    }

    __syncthreads();
    if (half == 0) {
        #pragma unroll
        for (int kk = 0; kk < 16; ++kk) {
            const int o = o0 + kk;
            if (o >= lim) break;
            if (o < DBN) xs[o * 64 + lane] = av[kk];
        }
    }
    __syncthreads();
    if (half == 0 && t < 64) {
        float m = -1e30f;
        #pragma unroll
        for (int d = 0; d < DBN; ++d) m = fmaxf(m, xs[d * 64 + t]);
        float s = 0.f;
        #pragma unroll
        for (int d = 0; d < DBN; ++d) s += expf(xs[d * 64 + t] - m);
        msum[pix0 + t] = make_float2(m, 1.0f / s);
    }
}

__global__ __launch_bounds__(256) void k_geom_only(
        const float* __restrict__ rots, const float* __restrict__ intrins,
        const float* __restrict__ trans,
        unsigned short* __restrict__ cell16, unsigned* __restrict__ cellofs) {
    __shared__ float combs[B_ * N_ * 9];
    __shared__ float trs[B_ * N_ * 3];
    const int t = threadIdx.x;
    if (t < B_ * N_) comb_cam(rots + t * 9, intrins + t * 9, &combs[t * 9]);
    if (t < B_ * N_ * 3) trs[t] = trans[t];
    __syncthreads();

    const int pt = blockIdx.x * 256 + t;
    const int c = geom_cell(pt, combs, trs);
    cell16[pt] = (c >= 0) ? (unsigned short)c : (unsigned short)0xFFFFu;

    const int lane = t & 63;
    unsigned long long active = __ballot(c >= 0);
    while (active) {
        const int leader = (int)__ffsll((unsigned long long)active) - 1;
        const int lc = __shfl(c, leader);
        const unsigned long long same = __ballot(c == lc);
        if (lane == leader)
            atomicAdd(&cellofs[lc], (unsigned)__popcll(same));
        active &= ~same;
    }
}

__global__ __launch_bounds__(1024) void k_scan1024(unsigned* __restrict__ cellofs) {
    __shared__ unsigned lds[2][1024];
    const int t = threadIdx.x;
    uint4 u[8];
    const uint4* src4 = (const uint4*)cellofs + (size_t)t * 8;
    #pragma unroll
    for (int i = 0; i < 8; ++i) u[i] = src4[i];
    unsigned vv[32];
    unsigned run = 0;
    #pragma unroll
    for (int i = 0; i < 8; ++i) {
        vv[i*4+0] = run; run += u[i].x;
        vv[i*4+1] = run; run += u[i].y;
        vv[i*4+2] = run; run += u[i].z;
        vv[i*4+3] = run; run += u[i].w;
    }
    lds[0][t] = run;
    __syncthreads();
    int src = 0;
    for (int off = 1; off < 1024; off <<= 1) {
        unsigned val = lds[src][t];
        if (t >= off) val += lds[src][t - off];
        lds[1 - src][t] = val;
        __syncthreads();
        src = 1 - src;
    }
    const unsigned base = (t == 0) ? 0u : lds[src][t - 1];
    uint4* dst4 = (uint4*)cellofs + (size_t)t * 8;
    #pragma unroll
    for (int i = 0; i < 8; ++i) {
        uint4 w;
        w.x = base + vv[i*4+0];
        w.y = base + vv[i*4+1];
        w.z = base + vv[i*4+2];
        w.w = base + vv[i*4+3];
        dst4[i] = w;
    }
}

// ---------------------------------------------------------------------------
extern "C" void kernel_launch(void* const* d_in, const int* in_sizes, int n_in,
                              void* d_out, int out_size, void* d_ws, size_t ws_size,
                              hipStream_t stream) {
    const float* x       = (const float*)d_in[0];
    const float* rots    = (const float*)d_in[1];
    const float* trans   = (const float*)d_in[2];
    const float* intrins = (const float*)d_in[3];
    const float* depth_w = (const float*)d_in[4];
    const float* depth_b = (const float*)d_in[5];
    float* out = (float*)d_out;
    char* ws = (char*)d_ws;

    const int gblocks = (NPTS / TCH + 3) / 4;       // 3894

    // ---- Tier A: non-aliased layout (needs 34,353,664 B) ----
    if (ws_size >= 34353664) {
        float*    dlog    = (float*)   (ws + 0);            // 1,993,728 B
        float2*   msum    = (float2*)  (ws + 1993728);      //    67,584 B
        unsigned* cellofs = (unsigned*)(ws + 2061312);      //   131,072 B
        unsigned short* cell16 = (unsigned short*)(ws + 2192384); // 996,864 B
        float*    ctx_ws  = (float*)   (ws + 3189248);      // 2,162,688 B
        uint2*    srt     = (uint2*)   (ws + 5351936);      // 3,987,456 B
        float*    parts   = (float*)   (ws + 9339392);      // 16,625,664 B
        float*    tmp     = (float*)   (ws + 25965056);     // 8,388,608 B

        hipMemsetAsync(cellofs, 0, NCELL * sizeof(unsigned), stream);
        k_front<NK_><<<132 * 2 * NK_ + NPTS / 256, 256, 0, stream>>>(
            x, depth_w, rots, intrins, trans, parts, cell16, cellofs);
        k_mid<NK_><<<133, 256, 0, stream>>>(parts, depth_b, cellofs,
                                            dlog, ctx_ws, msum);
        k_fill<<<NPTS / 256, 256, 0, stream>>>(cell16, dlog, msum, cellofs,
                                               srt, (float4*)tmp);
        k_gather<<<gblocks, 256, 0, stream>>>(cellofs, srt, ctx_ws, tmp);
        k_transpose<<<512, 256, 0, stream>>>(tmp, out);
    } else {
        // ---- Tier B: round-9 aliased flow (proven 178 us) ----
        float* tmp      = (float*)(ws);                     // [0, 8MB)
        float* dlog     = (float*)(ws);                     // [0, 1.99MB)
        unsigned short* cell16 = (unsigned short*)(ws + 2097152);
        float2* msum    = (float2*)(ws + 3145728);
        float* ctx_ws   = (float*)(ws + 8388608);
        unsigned* cellofs = (unsigned*)(ws + 10551296);
        uint2* srt      = (uint2*)(ws + 10682368);          // -> 14.67 MB

        k_conv_mono<<<264, 256, 0, stream>>>(x, depth_w, depth_b, dlog,
                                             ctx_ws, msum, cellofs);
        k_geom_only<<<NPTS / 256, 256, 0, stream>>>(rots, intrins, trans,
                                                    cell16, cellofs);
        k_scan1024<<<1, 1024, 0, stream>>>(cellofs);
        k_fill<<<NPTS / 256, 256, 0, stream>>>(cell16, dlog, msum, cellofs,
                                               srt, nullptr);
        hipMemsetAsync(tmp, 0, (size_t)NCELL * OCH * sizeof(float), stream);
        k_gather<<<gblocks, 256, 0, stream>>>(cellofs, srt, ctx_ws, tmp);
        k_transpose<<<512, 256, 0, stream>>>(tmp, out);
    }
}